// Round 2
// baseline (1658.002 us; speedup 1.0000x reference)
//
#include <hip/hip_runtime.h>
#include <hip/hip_bf16.h>

// ModifiedGAT: 3-layer GAT, N=50000 nodes, E=800000 edges (+N self loops),
// layer0: 256 -> 4x64 concat, layers 1/2: 256->64, 64->64 (1 head).
// All float tensors are fp32 (per reference setup_inputs). Round-1 NaN was
// caused by misreading fp32 inputs as bf16 (low-half words decode to huge
// exponents -> Inf -> Inf-Inf = NaN).

__device__ __forceinline__ float elu_f(float x){ return x > 0.f ? x : expm1f(x); }
__device__ __forceinline__ float lrelu_f(float x){ return x > 0.f ? x : 0.2f * x; }

// ---------------- GEMM: C[M,NC] = A[M,K] @ B[K,NC], fp32 --------------------
__global__ __launch_bounds__(256) void gemm_kernel(const float* __restrict__ A,
                                                   const float* __restrict__ B,
                                                   float* __restrict__ C,
                                                   int M, int K, int NC){
  __shared__ float As[16][68];
  __shared__ float Bs[16][68];
  int tid = threadIdx.x;
  int tx = tid & 15, ty = tid >> 4;
  int row0 = blockIdx.y * 64;
  int col0 = blockIdx.x * 64;
  int arow = tid >> 2;          // 0..63
  int ak   = (tid & 3) << 2;    // 0,4,8,12
  int bk   = tid >> 4;          // 0..15
  int bcol = (tid & 15) << 2;   // 0..60
  float acc[4][4] = {};
  for(int kt = 0; kt < K; kt += 16){
    int gr = row0 + arow;
    float4 av = make_float4(0.f, 0.f, 0.f, 0.f);
    if(gr < M) av = *(const float4*)(A + (size_t)gr * K + kt + ak);
    As[ak+0][arow] = av.x; As[ak+1][arow] = av.y;
    As[ak+2][arow] = av.z; As[ak+3][arow] = av.w;
    float4 bv = *(const float4*)(B + (size_t)(kt + bk) * NC + col0 + bcol);
    Bs[bk][bcol+0] = bv.x; Bs[bk][bcol+1] = bv.y;
    Bs[bk][bcol+2] = bv.z; Bs[bk][bcol+3] = bv.w;
    __syncthreads();
    #pragma unroll
    for(int kk = 0; kk < 16; kk++){
      float a[4], b[4];
      #pragma unroll
      for(int i = 0; i < 4; i++) a[i] = As[kk][ty*4+i];
      #pragma unroll
      for(int j = 0; j < 4; j++) b[j] = Bs[kk][tx*4+j];
      #pragma unroll
      for(int i = 0; i < 4; i++)
        #pragma unroll
        for(int j = 0; j < 4; j++)
          acc[i][j] = fmaf(a[i], b[j], acc[i][j]);
    }
    __syncthreads();
  }
  #pragma unroll
  for(int i = 0; i < 4; i++){
    int gr = row0 + ty*4 + i;
    if(gr < M){
      float4 v = make_float4(acc[i][0], acc[i][1], acc[i][2], acc[i][3]);
      *(float4*)(C + (size_t)gr * NC + col0 + tx*4) = v;
    }
  }
}

// -------- attention logits, layer0: block=node, 4 waves = 4 heads ------------
__global__ __launch_bounds__(256) void al0_kernel(const float* __restrict__ h0,
                                                  const float* __restrict__ a_src,
                                                  const float* __restrict__ a_dst,
                                                  float* __restrict__ al_s,
                                                  float* __restrict__ al_d){
  int n = blockIdx.x; int t = threadIdx.x;
  float hv = h0[(size_t)n * 256 + t];
  float s = hv * a_src[t];
  float d = hv * a_dst[t];
  for(int off = 32; off > 0; off >>= 1){
    s += __shfl_down(s, off, 64);
    d += __shfl_down(d, off, 64);
  }
  if((t & 63) == 0){ int h = t >> 6; al_s[n*4+h] = s; al_d[n*4+h] = d; }
}

// -------- attention logits, 1 head 64-dim: 1 wave per node -------------------
__global__ __launch_bounds__(256) void al1_kernel(const float* __restrict__ g,
                                                  const float* __restrict__ a_src,
                                                  const float* __restrict__ a_dst,
                                                  float* __restrict__ al_s,
                                                  float* __restrict__ al_d, int N){
  int t = threadIdx.x; int lane = t & 63;
  int n = blockIdx.x * 4 + (t >> 6);
  if(n >= N) return;
  float hv = g[(size_t)n * 64 + lane];
  float s = hv * a_src[lane];
  float d = hv * a_dst[lane];
  for(int off = 32; off > 0; off >>= 1){
    s += __shfl_down(s, off, 64);
    d += __shfl_down(d, off, 64);
  }
  if(lane == 0){ al_s[n] = s; al_d[n] = d; }
}

// -------- per-edge logit + exp + denominator, layer0 (4 heads) ---------------
__global__ __launch_bounds__(256) void edge0_kernel(const int* __restrict__ ei,
                                                    const float4* __restrict__ al_s,
                                                    const float4* __restrict__ al_d,
                                                    float4* __restrict__ wbuf,
                                                    float* __restrict__ den,
                                                    int E, int Etot){
  int e = blockIdx.x * blockDim.x + threadIdx.x;
  if(e >= Etot) return;
  int s, d;
  if(e < E){ s = ei[e]; d = ei[E + e]; } else { s = e - E; d = s; }
  float4 as = al_s[s], ad = al_d[d];
  float4 w;
  w.x = expf(lrelu_f(as.x + ad.x));
  w.y = expf(lrelu_f(as.y + ad.y));
  w.z = expf(lrelu_f(as.z + ad.z));
  w.w = expf(lrelu_f(as.w + ad.w));
  wbuf[e] = w;
  atomicAdd(&den[d*4+0], w.x);
  atomicAdd(&den[d*4+1], w.y);
  atomicAdd(&den[d*4+2], w.z);
  atomicAdd(&den[d*4+3], w.w);
}

// -------- per-edge logit + exp + denominator, 1 head -------------------------
__global__ __launch_bounds__(256) void edge1_kernel(const int* __restrict__ ei,
                                                    const float* __restrict__ al_s,
                                                    const float* __restrict__ al_d,
                                                    float* __restrict__ wbuf,
                                                    float* __restrict__ den,
                                                    int E, int Etot){
  int e = blockIdx.x * blockDim.x + threadIdx.x;
  if(e >= Etot) return;
  int s, d;
  if(e < E){ s = ei[e]; d = ei[E + e]; } else { s = e - E; d = s; }
  float w = expf(lrelu_f(al_s[s] + al_d[d]));
  wbuf[e] = w;
  atomicAdd(&den[d], w);
}

// -------- aggregate layer0: block = edge, 256 features -----------------------
__global__ __launch_bounds__(256) void agg0_kernel(const int* __restrict__ ei,
                                                   const float* __restrict__ wbuf,
                                                   const float* __restrict__ h0,
                                                   float* __restrict__ acc,
                                                   int E, int Etot){
  int e = blockIdx.x;
  int t = threadIdx.x;
  int s, d;
  if(e < E){ s = ei[e]; d = ei[E + e]; } else { s = e - E; d = s; }
  float w = wbuf[e*4 + (t >> 6)];
  float v = w * h0[(size_t)s * 256 + t];
  atomicAdd(&acc[(size_t)d * 256 + t], v);
}

// -------- aggregate 1-head 64-dim: wave = edge -------------------------------
__global__ __launch_bounds__(256) void agg1_kernel(const int* __restrict__ ei,
                                                   const float* __restrict__ wbuf,
                                                   const float* __restrict__ g,
                                                   float* __restrict__ acc,
                                                   int E, int Etot){
  int t = threadIdx.x; int lane = t & 63;
  int e = blockIdx.x * 4 + (t >> 6);
  if(e >= Etot) return;
  int s, d;
  if(e < E){ s = ei[e]; d = ei[E + e]; } else { s = e - E; d = s; }
  float v = wbuf[e] * g[(size_t)s * 64 + lane];
  atomicAdd(&acc[(size_t)d * 64 + lane], v);
}

// -------- epilogues ----------------------------------------------------------
__global__ __launch_bounds__(256) void epi0_kernel(const float* __restrict__ acc,
                                                   const float* __restrict__ den,
                                                   const float* __restrict__ b,
                                                   float* __restrict__ out, int N){
  int idx = blockIdx.x * 256 + threadIdx.x;
  if(idx >= N * 256) return;
  int n = idx >> 8; int f = idx & 255; int h = f >> 6;
  float v = acc[idx] / (den[n*4+h] + 1e-16f) + b[f];
  out[idx] = elu_f(v);
}

__global__ __launch_bounds__(256) void epi1_kernel(const float* __restrict__ acc,
                                                   const float* __restrict__ den,
                                                   const float* __restrict__ b,
                                                   float* __restrict__ out, int N){
  int idx = blockIdx.x * 256 + threadIdx.x;
  if(idx >= N * 64) return;
  int n = idx >> 6; int f = idx & 63;
  out[idx] = elu_f(acc[idx] / (den[n] + 1e-16f) + b[f]);
}

extern "C" void kernel_launch(void* const* d_in, const int* in_sizes, int n_in,
                              void* d_out, int out_size, void* d_ws, size_t ws_size,
                              hipStream_t stream){
  const float* x   = (const float*)d_in[0];
  const int*   ei  = (const int*)d_in[1];
  const float* W0  = (const float*)d_in[2];
  const float* as0 = (const float*)d_in[3];
  const float* ad0 = (const float*)d_in[4];
  const float* b0  = (const float*)d_in[5];
  const float* W1  = (const float*)d_in[6];
  const float* as1 = (const float*)d_in[7];
  const float* ad1 = (const float*)d_in[8];
  const float* b1  = (const float*)d_in[9];
  const float* W2  = (const float*)d_in[10];
  const float* as2 = (const float*)d_in[11];
  const float* ad2 = (const float*)d_in[12];
  const float* b2  = (const float*)d_in[13];
  int N = in_sizes[0] / 256;
  int E = in_sizes[1] / 2;
  int Etot = E + N;

  size_t off = 0;
  auto alc = [&](size_t bytes) -> char* {
    char* p = (char*)d_ws + off;
    off += (bytes + 255) & ~(size_t)255;
    return p;
  };
  float* h0   = (float*)alc((size_t)N * 256 * 4);
  float* acc0 = (float*)alc((size_t)N * 256 * 4);
  float* wbuf = (float*)alc((size_t)Etot * 4 * 4);
  float* den  = (float*)alc((size_t)N * 4 * 4);
  float* als  = (float*)alc((size_t)N * 4 * 4);
  float* ald  = (float*)alc((size_t)N * 4 * 4);
  // layer-1/2 temporaries reuse the h0 region (dead after agg0)
  float* g1   = h0;
  float* acc1 = h0 + (size_t)N * 64;
  float* g2   = h0 + (size_t)N * 128;
  float* acc2 = h0 + (size_t)N * 192;
  float* h1in = acc0;   // epi0 writes in place
  float* h2in = acc1;   // epi1 writes in place

  int gemm_rows = (N + 63) / 64;

  // ---------------- Layer 0 ----------------
  hipMemsetAsync(acc0, 0, (size_t)N * 256 * 4, stream);
  hipMemsetAsync(den, 0, (size_t)N * 4 * 4, stream);
  gemm_kernel<<<dim3(4, gemm_rows), 256, 0, stream>>>(x, W0, h0, N, 256, 256);
  al0_kernel<<<N, 256, 0, stream>>>(h0, as0, ad0, als, ald);
  edge0_kernel<<<(Etot + 255) / 256, 256, 0, stream>>>(ei, (const float4*)als,
                                                       (const float4*)ald,
                                                       (float4*)wbuf, den, E, Etot);
  agg0_kernel<<<Etot, 256, 0, stream>>>(ei, wbuf, h0, acc0, E, Etot);
  epi0_kernel<<<(N * 256 + 255) / 256, 256, 0, stream>>>(acc0, den, b0, h1in, N);

  // ---------------- Layer 1 ----------------
  gemm_kernel<<<dim3(1, gemm_rows), 256, 0, stream>>>(h1in, W1, g1, N, 256, 64);
  hipMemsetAsync(acc1, 0, (size_t)N * 64 * 4, stream);
  hipMemsetAsync(den, 0, (size_t)N * 4, stream);
  al1_kernel<<<(N + 3) / 4, 256, 0, stream>>>(g1, as1, ad1, als, ald, N);
  edge1_kernel<<<(Etot + 255) / 256, 256, 0, stream>>>(ei, als, ald, wbuf, den, E, Etot);
  agg1_kernel<<<(Etot + 3) / 4, 256, 0, stream>>>(ei, wbuf, g1, acc1, E, Etot);
  epi1_kernel<<<(N * 64 + 255) / 256, 256, 0, stream>>>(acc1, den, b1, h2in, N);

  // ---------------- Layer 2 ----------------
  gemm_kernel<<<dim3(1, gemm_rows), 256, 0, stream>>>(h2in, W2, g2, N, 64, 64);
  hipMemsetAsync(acc2, 0, (size_t)N * 64 * 4, stream);
  hipMemsetAsync(den, 0, (size_t)N * 4, stream);
  al1_kernel<<<(N + 3) / 4, 256, 0, stream>>>(g2, as2, ad2, als, ald, N);
  edge1_kernel<<<(Etot + 255) / 256, 256, 0, stream>>>(ei, als, ald, wbuf, den, E, Etot);
  agg1_kernel<<<(Etot + 3) / 4, 256, 0, stream>>>(ei, wbuf, g2, acc2, E, Etot);
  epi1_kernel<<<(N * 64 + 255) / 256, 256, 0, stream>>>(acc2, den, b2,
                                                        (float*)d_out, N);
}

// Round 3
// 717.710 us; speedup vs baseline: 2.3101x; 2.3101x over previous
//
#include <hip/hip_runtime.h>
#include <hip/hip_bf16.h>

// ModifiedGAT, round 3: CSR (dst-sorted) aggregation, zero atomics in the
// feature path. Per call: counting-sort edges by dst (hist -> scan -> scatter),
// then per-layer: GEMM (with fused per-head attention-logit reduction in the
// epilogue) -> fused agg+softmax+bias+ELU (one dst node per block/wave,
// register accumulation, single coalesced write).

__device__ __forceinline__ float elu_f(float x){ return x > 0.f ? x : expm1f(x); }
__device__ __forceinline__ float lrelu_f(float x){ return x > 0.f ? x : 0.2f * x; }

// ---------------- GEMM: C[M,NC] = A[M,K] @ B[K,NC], fp32 --------------------
// Epilogue also computes per-head attention logits:
//   als[r*gridDim.x + bx] = sum_j C[r][col0+j] * asrc[col0+j]   (64 cols = 1 head)
__global__ __launch_bounds__(256) void gemm_kernel(const float* __restrict__ A,
                                                   const float* __restrict__ B,
                                                   float* __restrict__ C,
                                                   const float* __restrict__ asrc,
                                                   const float* __restrict__ adst,
                                                   float* __restrict__ als,
                                                   float* __restrict__ ald,
                                                   int M, int K, int NC){
  __shared__ float As[16][68];
  __shared__ float Bs[16][68];
  int tid = threadIdx.x;
  int tx = tid & 15, ty = tid >> 4;
  int row0 = blockIdx.y * 64;
  int col0 = blockIdx.x * 64;
  int arow = tid >> 2;          // 0..63
  int ak   = (tid & 3) << 2;    // 0,4,8,12
  int bk   = tid >> 4;          // 0..15
  int bcol = (tid & 15) << 2;   // 0..60
  float acc[4][4] = {};
  for(int kt = 0; kt < K; kt += 16){
    int gr = row0 + arow;
    float4 av = make_float4(0.f, 0.f, 0.f, 0.f);
    if(gr < M) av = *(const float4*)(A + (size_t)gr * K + kt + ak);
    As[ak+0][arow] = av.x; As[ak+1][arow] = av.y;
    As[ak+2][arow] = av.z; As[ak+3][arow] = av.w;
    float4 bv = *(const float4*)(B + (size_t)(kt + bk) * NC + col0 + bcol);
    Bs[bk][bcol+0] = bv.x; Bs[bk][bcol+1] = bv.y;
    Bs[bk][bcol+2] = bv.z; Bs[bk][bcol+3] = bv.w;
    __syncthreads();
    #pragma unroll
    for(int kk = 0; kk < 16; kk++){
      float a[4], b[4];
      #pragma unroll
      for(int i = 0; i < 4; i++) a[i] = As[kk][ty*4+i];
      #pragma unroll
      for(int j = 0; j < 4; j++) b[j] = Bs[kk][tx*4+j];
      #pragma unroll
      for(int i = 0; i < 4; i++)
        #pragma unroll
        for(int j = 0; j < 4; j++)
          acc[i][j] = fmaf(a[i], b[j], acc[i][j]);
    }
    __syncthreads();
  }
  // store C tile
  #pragma unroll
  for(int i = 0; i < 4; i++){
    int gr = row0 + ty*4 + i;
    if(gr < M){
      float4 v = make_float4(acc[i][0], acc[i][1], acc[i][2], acc[i][3]);
      *(float4*)(C + (size_t)gr * NC + col0 + tx*4) = v;
    }
  }
  // fused attention-logit partial: this block covers exactly one head's cols
  float vs[4], vd[4];
  #pragma unroll
  for(int i = 0; i < 4; i++){
    float ps = 0.f, pd = 0.f;
    #pragma unroll
    for(int j = 0; j < 4; j++){
      float a_s = asrc[col0 + tx*4 + j];
      float a_d = adst[col0 + tx*4 + j];
      ps = fmaf(acc[i][j], a_s, ps);
      pd = fmaf(acc[i][j], a_d, pd);
    }
    vs[i] = ps; vd[i] = pd;
  }
  #pragma unroll
  for(int off = 8; off > 0; off >>= 1){
    #pragma unroll
    for(int i = 0; i < 4; i++){
      vs[i] += __shfl_down(vs[i], off, 16);
      vd[i] += __shfl_down(vd[i], off, 16);
    }
  }
  if(tx == 0){
    int hstride = gridDim.x;   // 4 for layer0, 1 for layers 1/2
    #pragma unroll
    for(int i = 0; i < 4; i++){
      int gr = row0 + ty*4 + i;
      if(gr < M){
        als[(size_t)gr * hstride + blockIdx.x] = vs[i];
        ald[(size_t)gr * hstride + blockIdx.x] = vd[i];
      }
    }
  }
}

// ---------------- CSR build: counting sort by dst ----------------------------
__global__ __launch_bounds__(256) void hist_kernel(const int* __restrict__ ei,
                                                   int* __restrict__ cnt,
                                                   int E, int Etot){
  int e = blockIdx.x * 256 + threadIdx.x;
  if(e >= Etot) return;
  int d = (e < E) ? ei[E + e] : (e - E);
  atomicAdd(&cnt[d], 1);
}

__global__ __launch_bounds__(256) void blocksum_kernel(const int* __restrict__ cnt,
                                                       int* __restrict__ bsum, int N){
  __shared__ int sm[256];
  int t = threadIdx.x;
  int i = blockIdx.x * 256 + t;
  sm[t] = (i < N) ? cnt[i] : 0;
  __syncthreads();
  for(int off = 128; off > 0; off >>= 1){
    if(t < off) sm[t] += sm[t + off];
    __syncthreads();
  }
  if(t == 0) bsum[blockIdx.x] = sm[0];
}

// single block: exclusive scan of bsum[nb], nb <= 256
__global__ __launch_bounds__(256) void scanb_kernel(int* __restrict__ bsum, int nb){
  __shared__ int sm[256];
  int t = threadIdx.x;
  int v = (t < nb) ? bsum[t] : 0;
  sm[t] = v;
  __syncthreads();
  for(int off = 1; off < 256; off <<= 1){
    int x = 0;
    if(t >= off) x = sm[t - off];
    __syncthreads();
    sm[t] += x;
    __syncthreads();
  }
  if(t < nb) bsum[t] = sm[t] - v;   // exclusive
}

__global__ __launch_bounds__(256) void scan2_kernel(const int* __restrict__ cnt,
                                                    const int* __restrict__ bsum,
                                                    int* __restrict__ rowptr,
                                                    int* __restrict__ cursor,
                                                    int N, int Etot){
  __shared__ int sm[256];
  int t = threadIdx.x;
  int i = blockIdx.x * 256 + t;
  int v = (i < N) ? cnt[i] : 0;
  sm[t] = v;
  __syncthreads();
  for(int off = 1; off < 256; off <<= 1){
    int x = 0;
    if(t >= off) x = sm[t - off];
    __syncthreads();
    sm[t] += x;
    __syncthreads();
  }
  if(i < N){
    int ex = sm[t] - v + bsum[blockIdx.x];
    rowptr[i] = ex;
    cursor[i] = ex;
    if(i == N - 1) rowptr[N] = Etot;
  }
}

__global__ __launch_bounds__(256) void scatter_kernel(const int* __restrict__ ei,
                                                      int* __restrict__ cursor,
                                                      int* __restrict__ esrc,
                                                      int E, int Etot){
  int e = blockIdx.x * 256 + threadIdx.x;
  if(e >= Etot) return;
  int s, d;
  if(e < E){ s = ei[e]; d = ei[E + e]; } else { s = e - E; d = s; }
  int pos = atomicAdd(&cursor[d], 1);
  esrc[pos] = s;
}

// ---------------- fused aggregate + softmax + bias + ELU ---------------------
// layer0: one block (256 thr) per dst node; thread t = feature t, head = t>>6
__global__ __launch_bounds__(256) void agg0_kernel(const int* __restrict__ rowptr,
                                                   const int* __restrict__ esrc,
                                                   const float* __restrict__ h0,
                                                   const float* __restrict__ als,
                                                   const float* __restrict__ ald,
                                                   const float* __restrict__ b,
                                                   float* __restrict__ out){
  int n = blockIdx.x;
  int t = threadIdx.x;
  int h = t >> 6;
  int beg = rowptr[n], end = rowptr[n + 1];
  float ad = ald[(size_t)n * 4 + h];
  float acc = 0.f, den = 0.f;
  for(int e = beg; e < end; e++){
    int s = esrc[e];
    float w = expf(lrelu_f(als[(size_t)s * 4 + h] + ad));
    acc = fmaf(w, h0[(size_t)s * 256 + t], acc);
    den += w;
  }
  out[(size_t)n * 256 + t] = elu_f(acc / (den + 1e-16f) + b[t]);
}

// layers 1/2: one wave per dst node (4 nodes/block); lane = feature
__global__ __launch_bounds__(256) void agg1_kernel(const int* __restrict__ rowptr,
                                                   const int* __restrict__ esrc,
                                                   const float* __restrict__ g,
                                                   const float* __restrict__ als,
                                                   const float* __restrict__ ald,
                                                   const float* __restrict__ b,
                                                   float* __restrict__ out, int N){
  int t = threadIdx.x;
  int lane = t & 63;
  int n = blockIdx.x * 4 + (t >> 6);
  if(n >= N) return;
  int beg = rowptr[n], end = rowptr[n + 1];
  float ad = ald[n];
  float acc = 0.f, den = 0.f;
  for(int e = beg; e < end; e++){
    int s = esrc[e];
    float w = expf(lrelu_f(als[s] + ad));
    acc = fmaf(w, g[(size_t)s * 64 + lane], acc);
    den += w;
  }
  out[(size_t)n * 64 + lane] = elu_f(acc / (den + 1e-16f) + b[lane]);
}

extern "C" void kernel_launch(void* const* d_in, const int* in_sizes, int n_in,
                              void* d_out, int out_size, void* d_ws, size_t ws_size,
                              hipStream_t stream){
  const float* x   = (const float*)d_in[0];
  const int*   ei  = (const int*)d_in[1];
  const float* W0  = (const float*)d_in[2];
  const float* as0 = (const float*)d_in[3];
  const float* ad0 = (const float*)d_in[4];
  const float* b0  = (const float*)d_in[5];
  const float* W1  = (const float*)d_in[6];
  const float* as1 = (const float*)d_in[7];
  const float* ad1 = (const float*)d_in[8];
  const float* b1  = (const float*)d_in[9];
  const float* W2  = (const float*)d_in[10];
  const float* as2 = (const float*)d_in[11];
  const float* ad2 = (const float*)d_in[12];
  const float* b2  = (const float*)d_in[13];
  int N = in_sizes[0] / 256;
  int E = in_sizes[1] / 2;
  int Etot = E + N;

  size_t off = 0;
  auto alc = [&](size_t bytes) -> char* {
    char* p = (char*)d_ws + off;
    off += (bytes + 255) & ~(size_t)255;
    return p;
  };
  float* bufA = (float*)alc((size_t)N * 256 * 4);   // h0 -> later g1/h2/g2
  float* bufB = (float*)alc((size_t)N * 256 * 4);   // h1 (layer0 out)
  float* als  = (float*)alc((size_t)N * 4 * 4);
  float* ald  = (float*)alc((size_t)N * 4 * 4);
  int* esrc   = (int*)alc((size_t)Etot * 4);
  int* rowptr = (int*)alc((size_t)(N + 1) * 4);
  int* cnt    = (int*)alc((size_t)N * 4);
  int* cursor = (int*)alc((size_t)N * 4);
  int* bsum   = (int*)alc(256 * 4);

  float* h0 = bufA;
  float* h1 = bufB;
  float* g1 = bufA;                       // dead h0 region reused
  float* h2 = bufA + (size_t)N * 64;
  float* g2 = bufA + (size_t)N * 128;

  int nb = (N + 255) / 256;
  int eb = (Etot + 255) / 256;
  int gemm_rows = (N + 63) / 64;

  // ---- CSR build (dst-sorted) ----
  hipMemsetAsync(cnt, 0, (size_t)N * 4, stream);
  hist_kernel<<<eb, 256, 0, stream>>>(ei, cnt, E, Etot);
  blocksum_kernel<<<nb, 256, 0, stream>>>(cnt, bsum, N);
  scanb_kernel<<<1, 256, 0, stream>>>(bsum, nb);
  scan2_kernel<<<nb, 256, 0, stream>>>(cnt, bsum, rowptr, cursor, N, Etot);
  scatter_kernel<<<eb, 256, 0, stream>>>(ei, cursor, esrc, E, Etot);

  // ---- Layer 0: 256 -> 4x64 concat ----
  gemm_kernel<<<dim3(4, gemm_rows), 256, 0, stream>>>(x, W0, h0, as0, ad0,
                                                      als, ald, N, 256, 256);
  agg0_kernel<<<N, 256, 0, stream>>>(rowptr, esrc, h0, als, ald, b0, h1);

  // ---- Layer 1: 256 -> 64 ----
  gemm_kernel<<<dim3(1, gemm_rows), 256, 0, stream>>>(h1, W1, g1, as1, ad1,
                                                      als, ald, N, 256, 64);
  agg1_kernel<<<(N + 3) / 4, 256, 0, stream>>>(rowptr, esrc, g1, als, ald, b1, h2, N);

  // ---- Layer 2: 64 -> 64 ----
  gemm_kernel<<<dim3(1, gemm_rows), 256, 0, stream>>>(h2, W2, g2, as2, ad2,
                                                      als, ald, N, 64, 64);
  agg1_kernel<<<(N + 3) / 4, 256, 0, stream>>>(rowptr, esrc, g2, als, ald, b2,
                                               (float*)d_out, N);
}

// Round 4
// 688.768 us; speedup vs baseline: 2.4072x; 1.0420x over previous
//
#include <hip/hip_runtime.h>
#include <hip/hip_bf16.h>

// ModifiedGAT, round 4:
//  - CSR aggregation with per-edge weights PRECOMPUTED (exp hoisted out of the
//    per-feature inner loop; round-3 agg0 was VALU-bound at 66% on redundant exps)
//  - all three GEMMs moved to bf16 MFMA (16x16x32), fp32 accumulate.
//    A-frag: A[m=lane&15][k=(lane>>4)*8+j] -> one short8 (16B) load
//    B-frag: B[k][n=lane&15]; weights pre-transposed to Bp[n*K+k] -> short8 load
//    C/D:    col=lane&15, row=(lane>>4)*4+reg  (HW-verified layouts)
//  - agg epilogues emit bf16 activations directly (next GEMM's A operand)

typedef unsigned short ushort_t;
typedef __attribute__((ext_vector_type(8))) short short8;
typedef __attribute__((ext_vector_type(4))) float f32x4;

__device__ __forceinline__ float elu_f(float x){ return x > 0.f ? x : expm1f(x); }
__device__ __forceinline__ float lrelu_f(float x){ return x > 0.f ? x : 0.2f * x; }
__device__ __forceinline__ ushort_t f2b(float f){
  union { float f; unsigned u; } v; v.f = f;
  unsigned r = v.u + 0x7fff + ((v.u >> 16) & 1);   // round-to-nearest-even
  return (ushort_t)(r >> 16);
}

// ---------------- fp32 -> bf16 bulk convert ---------------------------------
__global__ __launch_bounds__(256) void f2b_kernel(const float4* __restrict__ in,
                                                  ushort4* __restrict__ out, int n4){
  int i = blockIdx.x * 256 + threadIdx.x;
  if(i >= n4) return;
  float4 v = in[i];
  ushort4 o;
  o.x = f2b(v.x); o.y = f2b(v.y); o.z = f2b(v.z); o.w = f2b(v.w);
  out[i] = o;
}

// ---------------- weight transpose+convert: Bp[n*K+k] = bf16(W[k*NC+n]) -----
__global__ __launch_bounds__(256) void wt_kernel(const float* __restrict__ W,
                                                 ushort_t* __restrict__ Bp,
                                                 int K, int NC){
  int i = blockIdx.x * 256 + threadIdx.x;
  if(i >= K * NC) return;
  int k = i / NC, n = i - k * NC;
  Bp[(size_t)n * K + k] = f2b(W[i]);
}

// ---------------- MFMA GEMM: C[M,NC] = A[M,K] @ B[K,NC] ---------------------
// A bf16 row-major, B pre-transposed bf16 Bp[n*K+k], C fp32.
// One wave computes a 16x64 tile. Epilogue: per-row logits vs asrc/adst for
// this 64-col block (one head), reduced across the 16 col-lanes.
__global__ __launch_bounds__(256) void mfma_gemm(const ushort_t* __restrict__ A,
                                                 const ushort_t* __restrict__ Bp,
                                                 float* __restrict__ C,
                                                 const float* __restrict__ asrc,
                                                 const float* __restrict__ adst,
                                                 float* __restrict__ als,
                                                 float* __restrict__ ald,
                                                 int M, int K, int NC){
  int wave = threadIdx.x >> 6;
  int lane = threadIdx.x & 63;
  int rowt = blockIdx.x * 4 + wave;        // 16-row tile
  if(rowt * 16 >= M) return;
  int colb = blockIdx.y;                   // 64-col block (= head index)
  int m = lane & 15, q = lane >> 4;        // q: 0..3
  const ushort_t* Arow = A + (size_t)(rowt * 16 + m) * K + q * 8;
  const ushort_t* Bq   = Bp + (size_t)(colb * 64 + m) * K + q * 8;
  f32x4 acc[4] = {};
  for(int k0 = 0; k0 < K; k0 += 32){
    short8 av = *(const short8*)(Arow + k0);
    #pragma unroll
    for(int j = 0; j < 4; j++){
      short8 bv = *(const short8*)(Bq + (size_t)j * 16 * K + k0);
      acc[j] = __builtin_amdgcn_mfma_f32_16x16x32_bf16(av, bv, acc[j], 0, 0, 0);
    }
  }
  // store C
  #pragma unroll
  for(int j = 0; j < 4; j++){
    int col = colb * 64 + j * 16 + m;
    #pragma unroll
    for(int i = 0; i < 4; i++){
      int r = rowt * 16 + q * 4 + i;
      C[(size_t)r * NC + col] = acc[j][i];
    }
  }
  // fused attention logits for this head (64-col block)
  float vs[4] = {0,0,0,0}, vd[4] = {0,0,0,0};
  #pragma unroll
  for(int j = 0; j < 4; j++){
    int col = colb * 64 + j * 16 + m;
    float a_s = asrc[col], a_d = adst[col];
    #pragma unroll
    for(int i = 0; i < 4; i++){
      vs[i] = fmaf(acc[j][i], a_s, vs[i]);
      vd[i] = fmaf(acc[j][i], a_d, vd[i]);
    }
  }
  #pragma unroll
  for(int off = 8; off > 0; off >>= 1){
    #pragma unroll
    for(int i = 0; i < 4; i++){
      vs[i] += __shfl_down(vs[i], off, 16);
      vd[i] += __shfl_down(vd[i], off, 16);
    }
  }
  if(m == 0){
    int hstride = gridDim.y;
    #pragma unroll
    for(int i = 0; i < 4; i++){
      int r = rowt * 16 + q * 4 + i;
      als[(size_t)r * hstride + colb] = vs[i];
      ald[(size_t)r * hstride + colb] = vd[i];
    }
  }
}

// ---------------- CSR build: counting sort by dst ----------------------------
__global__ __launch_bounds__(256) void hist_kernel(const int* __restrict__ ei,
                                                   int* __restrict__ cnt,
                                                   int E, int Etot){
  int e = blockIdx.x * 256 + threadIdx.x;
  if(e >= Etot) return;
  int d = (e < E) ? ei[E + e] : (e - E);
  atomicAdd(&cnt[d], 1);
}

__global__ __launch_bounds__(256) void blocksum_kernel(const int* __restrict__ cnt,
                                                       int* __restrict__ bsum, int N){
  __shared__ int sm[256];
  int t = threadIdx.x;
  int i = blockIdx.x * 256 + t;
  sm[t] = (i < N) ? cnt[i] : 0;
  __syncthreads();
  for(int off = 128; off > 0; off >>= 1){
    if(t < off) sm[t] += sm[t + off];
    __syncthreads();
  }
  if(t == 0) bsum[blockIdx.x] = sm[0];
}

__global__ __launch_bounds__(256) void scanb_kernel(int* __restrict__ bsum, int nb){
  __shared__ int sm[256];
  int t = threadIdx.x;
  int v = (t < nb) ? bsum[t] : 0;
  sm[t] = v;
  __syncthreads();
  for(int off = 1; off < 256; off <<= 1){
    int x = 0;
    if(t >= off) x = sm[t - off];
    __syncthreads();
    sm[t] += x;
    __syncthreads();
  }
  if(t < nb) bsum[t] = sm[t] - v;   // exclusive
}

__global__ __launch_bounds__(256) void scan2_kernel(const int* __restrict__ cnt,
                                                    const int* __restrict__ bsum,
                                                    int* __restrict__ rowptr,
                                                    int* __restrict__ cursor,
                                                    int N, int Etot){
  __shared__ int sm[256];
  int t = threadIdx.x;
  int i = blockIdx.x * 256 + t;
  int v = (i < N) ? cnt[i] : 0;
  sm[t] = v;
  __syncthreads();
  for(int off = 1; off < 256; off <<= 1){
    int x = 0;
    if(t >= off) x = sm[t - off];
    __syncthreads();
    sm[t] += x;
    __syncthreads();
  }
  if(i < N){
    int ex = sm[t] - v + bsum[blockIdx.x];
    rowptr[i] = ex;
    cursor[i] = ex;
    if(i == N - 1) rowptr[N] = Etot;
  }
}

__global__ __launch_bounds__(256) void scatter_kernel(const int* __restrict__ ei,
                                                      int* __restrict__ cursor,
                                                      int* __restrict__ esrc,
                                                      int* __restrict__ dcsr,
                                                      int E, int Etot){
  int e = blockIdx.x * 256 + threadIdx.x;
  if(e >= Etot) return;
  int s, d;
  if(e < E){ s = ei[e]; d = ei[E + e]; } else { s = e - E; d = s; }
  int pos = atomicAdd(&cursor[d], 1);
  esrc[pos] = s;
  dcsr[pos] = d;
}

// ---------------- per-edge softmax weights (CSR order) -----------------------
__global__ __launch_bounds__(256) void wkern0(const int* __restrict__ esrc,
                                              const int* __restrict__ dcsr,
                                              const float4* __restrict__ als4,
                                              const float4* __restrict__ ald4,
                                              float4* __restrict__ wbuf, int Etot){
  int e = blockIdx.x * 256 + threadIdx.x;
  if(e >= Etot) return;
  float4 as = als4[esrc[e]], ad = ald4[dcsr[e]];
  float4 w;
  w.x = expf(lrelu_f(as.x + ad.x));
  w.y = expf(lrelu_f(as.y + ad.y));
  w.z = expf(lrelu_f(as.z + ad.z));
  w.w = expf(lrelu_f(as.w + ad.w));
  wbuf[e] = w;
}

__global__ __launch_bounds__(256) void wkern1(const int* __restrict__ esrc,
                                              const int* __restrict__ dcsr,
                                              const float* __restrict__ als,
                                              const float* __restrict__ ald,
                                              float* __restrict__ wbuf, int Etot){
  int e = blockIdx.x * 256 + threadIdx.x;
  if(e >= Etot) return;
  wbuf[e] = expf(lrelu_f(als[esrc[e]] + ald[dcsr[e]]));
}

// ---------------- fused aggregate + softmax-normalize + bias + ELU -----------
// layer0: one block (256 thr) per dst node; thread t = feature, head = t>>6.
// Emits bf16 (A operand of the next GEMM).
__global__ __launch_bounds__(256) void agg0_kernel(const int* __restrict__ rowptr,
                                                   const int* __restrict__ esrc,
                                                   const float* __restrict__ h0,
                                                   const float* __restrict__ wbuf,
                                                   const float* __restrict__ b,
                                                   ushort_t* __restrict__ out){
  int n = blockIdx.x;
  int t = threadIdx.x;
  int h = t >> 6;
  int beg = rowptr[n], end = rowptr[n + 1];
  float acc = 0.f, den = 0.f;
  for(int e = beg; e < end; e++){
    int s = esrc[e];
    float w = wbuf[(size_t)e * 4 + h];
    acc = fmaf(w, h0[((size_t)s << 8) + t], acc);
    den += w;
  }
  out[((size_t)n << 8) + t] = f2b(elu_f(acc / (den + 1e-16f) + b[t]));
}

// layers 1/2: one wave per dst node; lane = feature. OUTMODE 0 -> bf16, 1 -> fp32
template<int OUTMODE>
__global__ __launch_bounds__(256) void agg1_kernel(const int* __restrict__ rowptr,
                                                   const int* __restrict__ esrc,
                                                   const float* __restrict__ g,
                                                   const float* __restrict__ wbuf,
                                                   const float* __restrict__ b,
                                                   void* __restrict__ outp, int N){
  int t = threadIdx.x;
  int lane = t & 63;
  int n = blockIdx.x * 4 + (t >> 6);
  if(n >= N) return;
  int beg = rowptr[n], end = rowptr[n + 1];
  float acc = 0.f, den = 0.f;
  for(int e = beg; e < end; e++){
    int s = esrc[e];
    float w = wbuf[e];
    acc = fmaf(w, g[((size_t)s << 6) + lane], acc);
    den += w;
  }
  float v = elu_f(acc / (den + 1e-16f) + b[lane]);
  if(OUTMODE == 0) ((ushort_t*)outp)[((size_t)n << 6) + lane] = f2b(v);
  else             ((float*)outp)[((size_t)n << 6) + lane] = v;
}

extern "C" void kernel_launch(void* const* d_in, const int* in_sizes, int n_in,
                              void* d_out, int out_size, void* d_ws, size_t ws_size,
                              hipStream_t stream){
  const float* x   = (const float*)d_in[0];
  const int*   ei  = (const int*)d_in[1];
  const float* W0  = (const float*)d_in[2];
  const float* as0 = (const float*)d_in[3];
  const float* ad0 = (const float*)d_in[4];
  const float* b0  = (const float*)d_in[5];
  const float* W1  = (const float*)d_in[6];
  const float* as1 = (const float*)d_in[7];
  const float* ad1 = (const float*)d_in[8];
  const float* b1  = (const float*)d_in[9];
  const float* W2  = (const float*)d_in[10];
  const float* as2 = (const float*)d_in[11];
  const float* ad2 = (const float*)d_in[12];
  const float* b2  = (const float*)d_in[13];
  int N = in_sizes[0] / 256;
  int E = in_sizes[1] / 2;
  int Etot = E + N;

  size_t off = 0;
  auto alc = [&](size_t bytes) -> char* {
    char* p = (char*)d_ws + off;
    off += (bytes + 255) & ~(size_t)255;
    return p;
  };
  float*    bufA  = (float*)alc((size_t)N * 256 * 4);  // h0 fp32; later g1,g2
  ushort_t* xb    = (ushort_t*)alc((size_t)N * 256 * 2); // bf16 A; later h1b,h2b
  float*    wbuf  = (float*)alc((size_t)Etot * 4 * 4);
  float*    als   = (float*)alc((size_t)N * 4 * 4);
  float*    ald   = (float*)alc((size_t)N * 4 * 4);
  int*      esrc  = (int*)alc((size_t)Etot * 4);
  int*      dcsr  = (int*)alc((size_t)Etot * 4);
  int*      rowptr= (int*)alc((size_t)(N + 1) * 4);
  int*      cnt   = (int*)alc((size_t)N * 4);
  int*      cursor= (int*)alc((size_t)N * 4);
  int*      bsum  = (int*)alc(256 * 4);
  ushort_t* W0p   = (ushort_t*)alc(256 * 256 * 2);
  ushort_t* W1p   = (ushort_t*)alc(256 * 64 * 2);
  ushort_t* W2p   = (ushort_t*)alc(64 * 64 * 2);

  float*    h0  = bufA;
  float*    g1  = bufA;                    // h0 dead after agg0
  float*    g2  = bufA + (size_t)N * 64;
  ushort_t* h1b = xb;                      // xb dead after GEMM0
  ushort_t* h2b = xb;                      // h1b dead after GEMM1

  int nb = (N + 255) / 256;
  int eb = (Etot + 255) / 256;
  int rb = ((N + 15) / 16 + 3) / 4;        // MFMA row blocks (4 waves each)

  // ---- CSR build ----
  hipMemsetAsync(cnt, 0, (size_t)N * 4, stream);
  hist_kernel<<<eb, 256, 0, stream>>>(ei, cnt, E, Etot);
  blocksum_kernel<<<nb, 256, 0, stream>>>(cnt, bsum, N);
  scanb_kernel<<<1, 256, 0, stream>>>(bsum, nb);
  scan2_kernel<<<nb, 256, 0, stream>>>(cnt, bsum, rowptr, cursor, N, Etot);
  scatter_kernel<<<eb, 256, 0, stream>>>(ei, cursor, esrc, dcsr, E, Etot);

  // ---- operand prep ----
  f2b_kernel<<<(N * 64 + 255) / 256, 256, 0, stream>>>((const float4*)x,
                                                       (ushort4*)xb, N * 64);
  wt_kernel<<<(256 * 256 + 255) / 256, 256, 0, stream>>>(W0, W0p, 256, 256);
  wt_kernel<<<(256 * 64 + 255) / 256, 256, 0, stream>>>(W1, W1p, 256, 64);
  wt_kernel<<<(64 * 64 + 255) / 256, 256, 0, stream>>>(W2, W2p, 64, 64);

  // ---- Layer 0: 256 -> 4x64 concat ----
  mfma_gemm<<<dim3(rb, 4), 256, 0, stream>>>(xb, W0p, h0, as0, ad0, als, ald,
                                             N, 256, 256);
  wkern0<<<eb, 256, 0, stream>>>(esrc, dcsr, (const float4*)als,
                                 (const float4*)ald, (float4*)wbuf, Etot);
  agg0_kernel<<<N, 256, 0, stream>>>(rowptr, esrc, h0, wbuf, b0, h1b);

  // ---- Layer 1: 256 -> 64 ----
  mfma_gemm<<<dim3(rb, 1), 256, 0, stream>>>(h1b, W1p, g1, as1, ad1, als, ald,
                                             N, 256, 64);
  wkern1<<<eb, 256, 0, stream>>>(esrc, dcsr, als, ald, wbuf, Etot);
  agg1_kernel<0><<<(N + 3) / 4, 256, 0, stream>>>(rowptr, esrc, g1, wbuf, b1,
                                                  h2b, N);

  // ---- Layer 2: 64 -> 64 ----
  mfma_gemm<<<dim3(rb, 1), 256, 0, stream>>>(h2b, W2p, g2, as2, ad2, als, ald,
                                             N, 64, 64);
  wkern1<<<eb, 256, 0, stream>>>(esrc, dcsr, als, ald, wbuf, Etot);
  agg1_kernel<1><<<(N + 3) / 4, 256, 0, stream>>>(rowptr, esrc, g2, wbuf, b2,
                                                  d_out, N);
}

// Round 5
// 598.363 us; speedup vs baseline: 2.7709x; 1.1511x over previous
//
#include <hip/hip_runtime.h>
#include <hip/hip_bf16.h>

// ModifiedGAT, round 5: gather-byte reduction.
//  - h0 and g1 stored bf16 (GEMM epilogue emits bf16); agg0 gathers 512B/edge
//    (was 1KB), layer-1 agg gathers 128B/edge (was 256B). Layer 2 stays fp32.
//  - agg0: 128 thr/node, uint loads = 2 bf16 features/lane (4B/lane coalesced).
//  - Round-4 evidence: agg0 VALUBusy 21%, HBM 30% -> gather-traffic bound at
//    ~4.6 TB/s effective; halving bytes/edge should ~halve its duration.

typedef unsigned short ushort_t;
typedef __attribute__((ext_vector_type(8))) short short8;
typedef __attribute__((ext_vector_type(4))) float f32x4;

__device__ __forceinline__ float elu_f(float x){ return x > 0.f ? x : expm1f(x); }
__device__ __forceinline__ float lrelu_f(float x){ return x > 0.f ? x : 0.2f * x; }
__device__ __forceinline__ ushort_t f2b(float f){
  union { float f; unsigned u; } v; v.f = f;
  unsigned r = v.u + 0x7fff + ((v.u >> 16) & 1);   // round-to-nearest-even
  return (ushort_t)(r >> 16);
}
__device__ __forceinline__ float b2f_lo(unsigned v){
  union { unsigned u; float f; } c; c.u = v << 16; return c.f;
}
__device__ __forceinline__ float b2f_hi(unsigned v){
  union { unsigned u; float f; } c; c.u = v & 0xffff0000u; return c.f;
}

// ---------------- fp32 -> bf16 bulk convert ---------------------------------
__global__ __launch_bounds__(256) void f2b_kernel(const float4* __restrict__ in,
                                                  ushort4* __restrict__ out, int n4){
  int i = blockIdx.x * 256 + threadIdx.x;
  if(i >= n4) return;
  float4 v = in[i];
  ushort4 o;
  o.x = f2b(v.x); o.y = f2b(v.y); o.z = f2b(v.z); o.w = f2b(v.w);
  out[i] = o;
}

// ---------------- weight transpose+convert: Bp[n*K+k] = bf16(W[k*NC+n]) -----
__global__ __launch_bounds__(256) void wt_kernel(const float* __restrict__ W,
                                                 ushort_t* __restrict__ Bp,
                                                 int K, int NC){
  int i = blockIdx.x * 256 + threadIdx.x;
  if(i >= K * NC) return;
  int k = i / NC, n = i - k * NC;
  Bp[(size_t)n * K + k] = f2b(W[i]);
}

// ---------------- MFMA GEMM: C[M,NC] = A[M,K] @ B[K,NC] ---------------------
// A bf16 row-major, B pre-transposed bf16 Bp[n*K+k].
// CMODE 0: C bf16, 1: C fp32. One wave computes a 16x64 tile; epilogue reduces
// per-row attention logits for this 64-col block (= one head).
template<int CMODE>
__global__ __launch_bounds__(256) void mfma_gemm(const ushort_t* __restrict__ A,
                                                 const ushort_t* __restrict__ Bp,
                                                 void* __restrict__ Cp,
                                                 const float* __restrict__ asrc,
                                                 const float* __restrict__ adst,
                                                 float* __restrict__ als,
                                                 float* __restrict__ ald,
                                                 int M, int K, int NC){
  int wave = threadIdx.x >> 6;
  int lane = threadIdx.x & 63;
  int rowt = blockIdx.x * 4 + wave;        // 16-row tile
  if(rowt * 16 >= M) return;
  int colb = blockIdx.y;                   // 64-col block (= head index)
  int m = lane & 15, q = lane >> 4;        // q: 0..3
  const ushort_t* Arow = A + (size_t)(rowt * 16 + m) * K + q * 8;
  const ushort_t* Bq   = Bp + (size_t)(colb * 64 + m) * K + q * 8;
  f32x4 acc[4] = {};
  for(int k0 = 0; k0 < K; k0 += 32){
    short8 av = *(const short8*)(Arow + k0);
    #pragma unroll
    for(int j = 0; j < 4; j++){
      short8 bv = *(const short8*)(Bq + (size_t)j * 16 * K + k0);
      acc[j] = __builtin_amdgcn_mfma_f32_16x16x32_bf16(av, bv, acc[j], 0, 0, 0);
    }
  }
  // store C
  #pragma unroll
  for(int j = 0; j < 4; j++){
    int col = colb * 64 + j * 16 + m;
    #pragma unroll
    for(int i = 0; i < 4; i++){
      int r = rowt * 16 + q * 4 + i;
      if(CMODE == 0) ((ushort_t*)Cp)[(size_t)r * NC + col] = f2b(acc[j][i]);
      else           ((float*)Cp)[(size_t)r * NC + col] = acc[j][i];
    }
  }
  // fused attention logits for this head (64-col block)
  float vs[4] = {0,0,0,0}, vd[4] = {0,0,0,0};
  #pragma unroll
  for(int j = 0; j < 4; j++){
    int col = colb * 64 + j * 16 + m;
    float a_s = asrc[col], a_d = adst[col];
    #pragma unroll
    for(int i = 0; i < 4; i++){
      vs[i] = fmaf(acc[j][i], a_s, vs[i]);
      vd[i] = fmaf(acc[j][i], a_d, vd[i]);
    }
  }
  #pragma unroll
  for(int off = 8; off > 0; off >>= 1){
    #pragma unroll
    for(int i = 0; i < 4; i++){
      vs[i] += __shfl_down(vs[i], off, 16);
      vd[i] += __shfl_down(vd[i], off, 16);
    }
  }
  if(m == 0){
    int hstride = gridDim.y;
    #pragma unroll
    for(int i = 0; i < 4; i++){
      int r = rowt * 16 + q * 4 + i;
      als[(size_t)r * hstride + colb] = vs[i];
      ald[(size_t)r * hstride + colb] = vd[i];
    }
  }
}

// ---------------- CSR build: counting sort by dst ----------------------------
__global__ __launch_bounds__(256) void hist_kernel(const int* __restrict__ ei,
                                                   int* __restrict__ cnt,
                                                   int E, int Etot){
  int e = blockIdx.x * 256 + threadIdx.x;
  if(e >= Etot) return;
  int d = (e < E) ? ei[E + e] : (e - E);
  atomicAdd(&cnt[d], 1);
}

__global__ __launch_bounds__(256) void blocksum_kernel(const int* __restrict__ cnt,
                                                       int* __restrict__ bsum, int N){
  __shared__ int sm[256];
  int t = threadIdx.x;
  int i = blockIdx.x * 256 + t;
  sm[t] = (i < N) ? cnt[i] : 0;
  __syncthreads();
  for(int off = 128; off > 0; off >>= 1){
    if(t < off) sm[t] += sm[t + off];
    __syncthreads();
  }
  if(t == 0) bsum[blockIdx.x] = sm[0];
}

__global__ __launch_bounds__(256) void scanb_kernel(int* __restrict__ bsum, int nb){
  __shared__ int sm[256];
  int t = threadIdx.x;
  int v = (t < nb) ? bsum[t] : 0;
  sm[t] = v;
  __syncthreads();
  for(int off = 1; off < 256; off <<= 1){
    int x = 0;
    if(t >= off) x = sm[t - off];
    __syncthreads();
    sm[t] += x;
    __syncthreads();
  }
  if(t < nb) bsum[t] = sm[t] - v;   // exclusive
}

__global__ __launch_bounds__(256) void scan2_kernel(const int* __restrict__ cnt,
                                                    const int* __restrict__ bsum,
                                                    int* __restrict__ rowptr,
                                                    int* __restrict__ cursor,
                                                    int N, int Etot){
  __shared__ int sm[256];
  int t = threadIdx.x;
  int i = blockIdx.x * 256 + t;
  int v = (i < N) ? cnt[i] : 0;
  sm[t] = v;
  __syncthreads();
  for(int off = 1; off < 256; off <<= 1){
    int x = 0;
    if(t >= off) x = sm[t - off];
    __syncthreads();
    sm[t] += x;
    __syncthreads();
  }
  if(i < N){
    int ex = sm[t] - v + bsum[blockIdx.x];
    rowptr[i] = ex;
    cursor[i] = ex;
    if(i == N - 1) rowptr[N] = Etot;
  }
}

__global__ __launch_bounds__(256) void scatter_kernel(const int* __restrict__ ei,
                                                      int* __restrict__ cursor,
                                                      int* __restrict__ esrc,
                                                      int* __restrict__ dcsr,
                                                      int E, int Etot){
  int e = blockIdx.x * 256 + threadIdx.x;
  if(e >= Etot) return;
  int s, d;
  if(e < E){ s = ei[e]; d = ei[E + e]; } else { s = e - E; d = s; }
  int pos = atomicAdd(&cursor[d], 1);
  esrc[pos] = s;
  dcsr[pos] = d;
}

// ---------------- per-edge softmax weights (CSR order) -----------------------
__global__ __launch_bounds__(256) void wkern0(const int* __restrict__ esrc,
                                              const int* __restrict__ dcsr,
                                              const float4* __restrict__ als4,
                                              const float4* __restrict__ ald4,
                                              float4* __restrict__ wbuf, int Etot){
  int e = blockIdx.x * 256 + threadIdx.x;
  if(e >= Etot) return;
  float4 as = als4[esrc[e]], ad = ald4[dcsr[e]];
  float4 w;
  w.x = expf(lrelu_f(as.x + ad.x));
  w.y = expf(lrelu_f(as.y + ad.y));
  w.z = expf(lrelu_f(as.z + ad.z));
  w.w = expf(lrelu_f(as.w + ad.w));
  wbuf[e] = w;
}

__global__ __launch_bounds__(256) void wkern1(const int* __restrict__ esrc,
                                              const int* __restrict__ dcsr,
                                              const float* __restrict__ als,
                                              const float* __restrict__ ald,
                                              float* __restrict__ wbuf, int Etot){
  int e = blockIdx.x * 256 + threadIdx.x;
  if(e >= Etot) return;
  wbuf[e] = expf(lrelu_f(als[esrc[e]] + ald[dcsr[e]]));
}

// ---------------- fused aggregate + softmax-normalize + bias + ELU -----------
// layer0: 128 thr/node; thread t handles features 2t,2t+1 (uint = 2 bf16),
// head = t>>5. Emits bf16 pairs (uint) for the next GEMM's A operand.
__global__ __launch_bounds__(128) void agg0_kernel(const int* __restrict__ rowptr,
                                                   const int* __restrict__ esrc,
                                                   const unsigned* __restrict__ h0b,
                                                   const float* __restrict__ wbuf,
                                                   const float* __restrict__ b,
                                                   unsigned* __restrict__ out){
  int n = blockIdx.x;
  int t = threadIdx.x;       // 0..127
  int h = t >> 5;
  int beg = rowptr[n], end = rowptr[n + 1];
  float a0 = 0.f, a1 = 0.f, den = 0.f;
  for(int e = beg; e < end; e++){
    int s = esrc[e];
    float w = wbuf[(size_t)e * 4 + h];
    unsigned v = h0b[((size_t)s << 7) + t];
    a0 = fmaf(w, b2f_lo(v), a0);
    a1 = fmaf(w, b2f_hi(v), a1);
    den += w;
  }
  float inv = 1.f / (den + 1e-16f);
  float v0 = elu_f(a0 * inv + b[2 * t]);
  float v1 = elu_f(a1 * inv + b[2 * t + 1]);
  out[((size_t)n << 7) + t] = (unsigned)f2b(v0) | ((unsigned)f2b(v1) << 16);
}

// layers 1/2: one wave per dst node; lane = feature.
// RMODE 0: bf16 input, 1: fp32 input.  OMODE 0: bf16 out, 1: fp32 out.
template<int RMODE, int OMODE>
__global__ __launch_bounds__(256) void agg1_kernel(const int* __restrict__ rowptr,
                                                   const int* __restrict__ esrc,
                                                   const void* __restrict__ gp,
                                                   const float* __restrict__ wbuf,
                                                   const float* __restrict__ b,
                                                   void* __restrict__ outp, int N){
  int t = threadIdx.x;
  int lane = t & 63;
  int n = blockIdx.x * 4 + (t >> 6);
  if(n >= N) return;
  int beg = rowptr[n], end = rowptr[n + 1];
  float acc = 0.f, den = 0.f;
  for(int e = beg; e < end; e++){
    int s = esrc[e];
    float w = wbuf[e];
    float g;
    if(RMODE == 0){
      union { unsigned u; float f; } c;
      c.u = ((unsigned)((const ushort_t*)gp)[((size_t)s << 6) + lane]) << 16;
      g = c.f;
    } else {
      g = ((const float*)gp)[((size_t)s << 6) + lane];
    }
    acc = fmaf(w, g, acc);
    den += w;
  }
  float v = elu_f(acc / (den + 1e-16f) + b[lane]);
  if(OMODE == 0) ((ushort_t*)outp)[((size_t)n << 6) + lane] = f2b(v);
  else           ((float*)outp)[((size_t)n << 6) + lane] = v;
}

extern "C" void kernel_launch(void* const* d_in, const int* in_sizes, int n_in,
                              void* d_out, int out_size, void* d_ws, size_t ws_size,
                              hipStream_t stream){
  const float* x   = (const float*)d_in[0];
  const int*   ei  = (const int*)d_in[1];
  const float* W0  = (const float*)d_in[2];
  const float* as0 = (const float*)d_in[3];
  const float* ad0 = (const float*)d_in[4];
  const float* b0  = (const float*)d_in[5];
  const float* W1  = (const float*)d_in[6];
  const float* as1 = (const float*)d_in[7];
  const float* ad1 = (const float*)d_in[8];
  const float* b1  = (const float*)d_in[9];
  const float* W2  = (const float*)d_in[10];
  const float* as2 = (const float*)d_in[11];
  const float* ad2 = (const float*)d_in[12];
  const float* b2  = (const float*)d_in[13];
  int N = in_sizes[0] / 256;
  int E = in_sizes[1] / 2;
  int Etot = E + N;

  size_t off = 0;
  auto alc = [&](size_t bytes) -> char* {
    char* p = (char*)d_ws + off;
    off += (bytes + 255) & ~(size_t)255;
    return p;
  };
  ushort_t* xb    = (ushort_t*)alc((size_t)N * 256 * 2); // x bf16; later h1b,h2b
  ushort_t* h0b   = (ushort_t*)alc((size_t)N * 256 * 2); // h0 bf16; later g1b,g2
  float*    wbuf  = (float*)alc((size_t)Etot * 4 * 4);
  float*    als   = (float*)alc((size_t)N * 4 * 4);
  float*    ald   = (float*)alc((size_t)N * 4 * 4);
  int*      esrc  = (int*)alc((size_t)Etot * 4);
  int*      dcsr  = (int*)alc((size_t)Etot * 4);
  int*      rowptr= (int*)alc((size_t)(N + 1) * 4);
  int*      cnt   = (int*)alc((size_t)N * 4);
  int*      cursor= (int*)alc((size_t)N * 4);
  int*      bsum  = (int*)alc(256 * 4);
  ushort_t* W0p   = (ushort_t*)alc(256 * 256 * 2);
  ushort_t* W1p   = (ushort_t*)alc(256 * 64 * 2);
  ushort_t* W2p   = (ushort_t*)alc(64 * 64 * 2);

  ushort_t* h1b = xb;                      // xb dead after GEMM0
  ushort_t* h2b = xb;                      // h1b dead after GEMM1
  ushort_t* g1b = h0b;                     // h0b dead after agg0
  float*    g2  = (float*)h0b;             // g1b dead after agg1-L1 (12.8<25.6MB)

  int nb = (N + 255) / 256;
  int eb = (Etot + 255) / 256;
  int rb = ((N + 15) / 16 + 3) / 4;        // MFMA row blocks (4 waves each)

  // ---- CSR build ----
  hipMemsetAsync(cnt, 0, (size_t)N * 4, stream);
  hist_kernel<<<eb, 256, 0, stream>>>(ei, cnt, E, Etot);
  blocksum_kernel<<<nb, 256, 0, stream>>>(cnt, bsum, N);
  scanb_kernel<<<1, 256, 0, stream>>>(bsum, nb);
  scan2_kernel<<<nb, 256, 0, stream>>>(cnt, bsum, rowptr, cursor, N, Etot);
  scatter_kernel<<<eb, 256, 0, stream>>>(ei, cursor, esrc, dcsr, E, Etot);

  // ---- operand prep ----
  f2b_kernel<<<(N * 64 + 255) / 256, 256, 0, stream>>>((const float4*)x,
                                                       (ushort4*)xb, N * 64);
  wt_kernel<<<(256 * 256 + 255) / 256, 256, 0, stream>>>(W0, W0p, 256, 256);
  wt_kernel<<<(256 * 64 + 255) / 256, 256, 0, stream>>>(W1, W1p, 256, 64);
  wt_kernel<<<(64 * 64 + 255) / 256, 256, 0, stream>>>(W2, W2p, 64, 64);

  // ---- Layer 0: 256 -> 4x64 concat ----
  mfma_gemm<0><<<dim3(rb, 4), 256, 0, stream>>>(xb, W0p, h0b, as0, ad0,
                                                als, ald, N, 256, 256);
  wkern0<<<eb, 256, 0, stream>>>(esrc, dcsr, (const float4*)als,
                                 (const float4*)ald, (float4*)wbuf, Etot);
  agg0_kernel<<<N, 128, 0, stream>>>(rowptr, esrc, (const unsigned*)h0b, wbuf,
                                     b0, (unsigned*)h1b);

  // ---- Layer 1: 256 -> 64 ----
  mfma_gemm<0><<<dim3(rb, 1), 256, 0, stream>>>(h1b, W1p, g1b, as1, ad1,
                                                als, ald, N, 256, 64);
  wkern1<<<eb, 256, 0, stream>>>(esrc, dcsr, als, ald, wbuf, Etot);
  agg1_kernel<0, 0><<<(N + 3) / 4, 256, 0, stream>>>(rowptr, esrc, g1b, wbuf,
                                                     b1, h2b, N);

  // ---- Layer 2: 64 -> 64 ----
  mfma_gemm<1><<<dim3(rb, 1), 256, 0, stream>>>(h2b, W2p, g2, as2, ad2,
                                                als, ald, N, 64, 64);
  wkern1<<<eb, 256, 0, stream>>>(esrc, dcsr, als, ald, wbuf, Etot);
  agg1_kernel<1, 1><<<(N + 3) / 4, 256, 0, stream>>>(rowptr, esrc, g2, wbuf,
                                                     b2, d_out, N);
}

// Round 6
// 465.665 us; speedup vs baseline: 3.5605x; 1.2850x over previous
//
#include <hip/hip_runtime.h>
#include <hip/hip_bf16.h>

// ModifiedGAT, round 6: dispatch-count + fusion round (20 -> 12 dispatches).
//  - exp/softmax-weight computation fused INTO the agg kernels (LDS/shfl
//    broadcast); wkern + wbuf + dcsr deleted; scatter writes halved.
//  - prep fused: histogram + x->bf16 + 3 weight transposes in ONE kernel.
//  - g2 stored bf16 (layer-2 gather 218->109 MB). All gathers now bf16.
//  - GEMM: 2 row-tiles per wave (B fragments reused in registers).

typedef unsigned short ushort_t;
typedef __attribute__((ext_vector_type(8))) short short8;
typedef __attribute__((ext_vector_type(4))) float f32x4;

__device__ __forceinline__ float elu_f(float x){ return x > 0.f ? x : expm1f(x); }
__device__ __forceinline__ float lrelu_f(float x){ return x > 0.f ? x : 0.2f * x; }
__device__ __forceinline__ ushort_t f2b(float f){
  union { float f; unsigned u; } v; v.f = f;
  unsigned r = v.u + 0x7fff + ((v.u >> 16) & 1);   // round-to-nearest-even
  return (ushort_t)(r >> 16);
}
__device__ __forceinline__ float b2f_lo(unsigned v){
  union { unsigned u; float f; } c; c.u = v << 16; return c.f;
}
__device__ __forceinline__ float b2f_hi(unsigned v){
  union { unsigned u; float f; } c; c.u = v & 0xffff0000u; return c.f;
}

// ---------------- fused prep: hist + x->bf16 + weight transposes -------------
__global__ __launch_bounds__(256) void prep_kernel(const int* __restrict__ ei,
                                                   int* __restrict__ cnt,
                                                   const float4* __restrict__ x4,
                                                   ushort4* __restrict__ xb4, int n4,
                                                   const float* __restrict__ W0,
                                                   ushort_t* __restrict__ W0p,
                                                   const float* __restrict__ W1,
                                                   ushort_t* __restrict__ W1p,
                                                   const float* __restrict__ W2,
                                                   ushort_t* __restrict__ W2p,
                                                   int E, int Etot, int eb, int fb){
  int bid = blockIdx.x; int t = threadIdx.x;
  if(bid < eb){
    int e = bid * 256 + t;
    if(e < Etot){
      int d = (e < E) ? ei[E + e] : (e - E);
      atomicAdd(&cnt[d], 1);
    }
  } else if(bid < eb + fb){
    int i = (bid - eb) * 256 + t;
    if(i < n4){
      float4 v = x4[i];
      ushort4 o;
      o.x = f2b(v.x); o.y = f2b(v.y); o.z = f2b(v.z); o.w = f2b(v.w);
      xb4[i] = o;
    }
  } else {
    int r = bid - eb - fb;
    if(r < 256){            // W0: 256x256
      int i = r * 256 + t; int k = i >> 8, n = i & 255;
      W0p[(size_t)n * 256 + k] = f2b(W0[i]);
    } else if(r < 320){     // W1: 256x64
      int i = (r - 256) * 256 + t; int k = i >> 6, n = i & 63;
      W1p[(size_t)n * 256 + k] = f2b(W1[i]);
    } else {                // W2: 64x64
      int i = (r - 320) * 256 + t; int k = i >> 6, n = i & 63;
      W2p[(size_t)n * 64 + k] = f2b(W2[i]);
    }
  }
}

// ---------------- MFMA GEMM: C[M,NC] = A[M,K] @ B[K,NC], 2 row-tiles/wave ---
__global__ __launch_bounds__(256) void mfma_gemm(const ushort_t* __restrict__ A,
                                                 const ushort_t* __restrict__ Bp,
                                                 ushort_t* __restrict__ Cp,
                                                 const float* __restrict__ asrc,
                                                 const float* __restrict__ adst,
                                                 float* __restrict__ als,
                                                 float* __restrict__ ald,
                                                 int M, int K, int NC){
  int wave = threadIdx.x >> 6;
  int lane = threadIdx.x & 63;
  int tile0 = (blockIdx.x * 4 + wave) * 2;   // first 16-row tile (M%16==0)
  if(tile0 * 16 >= M) return;
  bool two = (tile0 + 1) * 16 < M;
  int colb = blockIdx.y;
  int m = lane & 15, q = lane >> 4;
  const ushort_t* Ab = A + (size_t)(tile0 * 16 + m) * K + q * 8;
  const ushort_t* Bq = Bp + (size_t)(colb * 64 + m) * K + q * 8;
  f32x4 acc[2][4] = {};
  for(int k0 = 0; k0 < K; k0 += 32){
    short8 bv[4];
    #pragma unroll
    for(int j = 0; j < 4; j++) bv[j] = *(const short8*)(Bq + (size_t)j * 16 * K + k0);
    short8 a0 = *(const short8*)(Ab + k0);
    #pragma unroll
    for(int j = 0; j < 4; j++)
      acc[0][j] = __builtin_amdgcn_mfma_f32_16x16x32_bf16(a0, bv[j], acc[0][j], 0, 0, 0);
    if(two){
      short8 a1 = *(const short8*)(Ab + (size_t)16 * K + k0);
      #pragma unroll
      for(int j = 0; j < 4; j++)
        acc[1][j] = __builtin_amdgcn_mfma_f32_16x16x32_bf16(a1, bv[j], acc[1][j], 0, 0, 0);
    }
  }
  int hstride = gridDim.y;
  #pragma unroll
  for(int r = 0; r < 2; r++){
    if(r == 1 && !two) break;
    int rowt = tile0 + r;
    #pragma unroll
    for(int j = 0; j < 4; j++){
      int col = colb * 64 + j * 16 + m;
      #pragma unroll
      for(int i = 0; i < 4; i++){
        int rr = rowt * 16 + q * 4 + i;
        Cp[(size_t)rr * NC + col] = f2b(acc[r][j][i]);
      }
    }
    float vs[4] = {0,0,0,0}, vd[4] = {0,0,0,0};
    #pragma unroll
    for(int j = 0; j < 4; j++){
      int col = colb * 64 + j * 16 + m;
      float a_s = asrc[col], a_d = adst[col];
      #pragma unroll
      for(int i = 0; i < 4; i++){
        vs[i] = fmaf(acc[r][j][i], a_s, vs[i]);
        vd[i] = fmaf(acc[r][j][i], a_d, vd[i]);
      }
    }
    #pragma unroll
    for(int off = 8; off > 0; off >>= 1){
      #pragma unroll
      for(int i = 0; i < 4; i++){
        vs[i] += __shfl_down(vs[i], off, 16);
        vd[i] += __shfl_down(vd[i], off, 16);
      }
    }
    if(m == 0){
      #pragma unroll
      for(int i = 0; i < 4; i++){
        int rr = rowt * 16 + q * 4 + i;
        als[(size_t)rr * hstride + colb] = vs[i];
        ald[(size_t)rr * hstride + colb] = vd[i];
      }
    }
  }
}

// ---------------- CSR build ---------------------------------------------------
__global__ __launch_bounds__(256) void blocksum_kernel(const int* __restrict__ cnt,
                                                       int* __restrict__ bsum, int N){
  __shared__ int sm[256];
  int t = threadIdx.x;
  int i = blockIdx.x * 256 + t;
  sm[t] = (i < N) ? cnt[i] : 0;
  __syncthreads();
  for(int off = 128; off > 0; off >>= 1){
    if(t < off) sm[t] += sm[t + off];
    __syncthreads();
  }
  if(t == 0) bsum[blockIdx.x] = sm[0];
}

__global__ __launch_bounds__(256) void scanb_kernel(int* __restrict__ bsum, int nb){
  __shared__ int sm[256];
  int t = threadIdx.x;
  int v = (t < nb) ? bsum[t] : 0;
  sm[t] = v;
  __syncthreads();
  for(int off = 1; off < 256; off <<= 1){
    int x = 0;
    if(t >= off) x = sm[t - off];
    __syncthreads();
    sm[t] += x;
    __syncthreads();
  }
  if(t < nb) bsum[t] = sm[t] - v;   // exclusive
}

__global__ __launch_bounds__(256) void scan2_kernel(const int* __restrict__ cnt,
                                                    const int* __restrict__ bsum,
                                                    int* __restrict__ rowptr,
                                                    int* __restrict__ cursor,
                                                    int N, int Etot){
  __shared__ int sm[256];
  int t = threadIdx.x;
  int i = blockIdx.x * 256 + t;
  int v = (i < N) ? cnt[i] : 0;
  sm[t] = v;
  __syncthreads();
  for(int off = 1; off < 256; off <<= 1){
    int x = 0;
    if(t >= off) x = sm[t - off];
    __syncthreads();
    sm[t] += x;
    __syncthreads();
  }
  if(i < N){
    int ex = sm[t] - v + bsum[blockIdx.x];
    rowptr[i] = ex;
    cursor[i] = ex;
    if(i == N - 1) rowptr[N] = Etot;
  }
}

__global__ __launch_bounds__(256) void scatter_kernel(const int* __restrict__ ei,
                                                      int* __restrict__ cursor,
                                                      int* __restrict__ esrc,
                                                      int E, int Etot){
  int e = blockIdx.x * 256 + threadIdx.x;
  if(e >= Etot) return;
  int s, d;
  if(e < E){ s = ei[e]; d = ei[E + e]; } else { s = e - E; d = s; }
  int pos = atomicAdd(&cursor[d], 1);
  esrc[pos] = s;
}

// ---------------- fused agg: exp + aggregate + normalize + bias + ELU --------
__global__ __launch_bounds__(128) void agg0_kernel(const int* __restrict__ rowptr,
                                                   const int* __restrict__ esrc,
                                                   const unsigned* __restrict__ h0b,
                                                   const float4* __restrict__ als4,
                                                   const float4* __restrict__ ald4,
                                                   const float* __restrict__ b,
                                                   unsigned* __restrict__ out){
  __shared__ float sw[4 * 128];
  __shared__ int sS[128];
  int n = blockIdx.x;
  int t = threadIdx.x;       // 0..127
  int h = t >> 5;
  int beg = rowptr[n], end = rowptr[n + 1];
  float4 ad = ald4[n];
  float a0 = 0.f, a1 = 0.f, den = 0.f;
  for(int c0 = beg; c0 < end; c0 += 128){
    int ce = min(end - c0, 128);
    if(t < ce){
      int s = esrc[c0 + t];
      float4 as = als4[s];
      sS[t] = s;
      sw[t]       = expf(lrelu_f(as.x + ad.x));
      sw[128 + t] = expf(lrelu_f(as.y + ad.y));
      sw[256 + t] = expf(lrelu_f(as.z + ad.z));
      sw[384 + t] = expf(lrelu_f(as.w + ad.w));
    }
    __syncthreads();
    for(int i = 0; i < ce; i++){
      int s = sS[i];
      float w = sw[(h << 7) + i];
      unsigned v = h0b[((size_t)s << 7) + t];
      a0 = fmaf(w, b2f_lo(v), a0);
      a1 = fmaf(w, b2f_hi(v), a1);
      den += w;
    }
    __syncthreads();
  }
  float inv = 1.f / (den + 1e-16f);
  float v0 = elu_f(a0 * inv + b[2 * t]);
  float v1 = elu_f(a1 * inv + b[2 * t + 1]);
  out[((size_t)n << 7) + t] = (unsigned)f2b(v0) | ((unsigned)f2b(v1) << 16);
}

// layers 1/2: one wave per dst node; lane = feature; bf16 gather; shfl bcast.
template<int OMODE>
__global__ __launch_bounds__(256) void agg1_kernel(const int* __restrict__ rowptr,
                                                   const int* __restrict__ esrc,
                                                   const ushort_t* __restrict__ gb,
                                                   const float* __restrict__ als,
                                                   const float* __restrict__ ald,
                                                   const float* __restrict__ b,
                                                   void* __restrict__ outp, int N){
  int t = threadIdx.x;
  int lane = t & 63;
  int n = blockIdx.x * 4 + (t >> 6);
  if(n >= N) return;
  int beg = rowptr[n], end = rowptr[n + 1];
  float ad = ald[n];
  float acc = 0.f, den = 0.f;
  for(int c0 = beg; c0 < end; c0 += 64){
    int ce = min(end - c0, 64);
    int s = 0; float w = 0.f;
    if(lane < ce){
      s = esrc[c0 + lane];
      w = expf(lrelu_f(als[s] + ad));
    }
    for(int i = 0; i < ce; i++){
      int si = __shfl(s, i, 64);
      float wi = __shfl(w, i, 64);
      union { unsigned u; float f; } c;
      c.u = ((unsigned)gb[((size_t)si << 6) + lane]) << 16;
      acc = fmaf(wi, c.f, acc);
      den += wi;
    }
  }
  float v = elu_f(acc / (den + 1e-16f) + b[lane]);
  if(OMODE == 0) ((ushort_t*)outp)[((size_t)n << 6) + lane] = f2b(v);
  else           ((float*)outp)[((size_t)n << 6) + lane] = v;
}

extern "C" void kernel_launch(void* const* d_in, const int* in_sizes, int n_in,
                              void* d_out, int out_size, void* d_ws, size_t ws_size,
                              hipStream_t stream){
  const float* x   = (const float*)d_in[0];
  const int*   ei  = (const int*)d_in[1];
  const float* W0  = (const float*)d_in[2];
  const float* as0 = (const float*)d_in[3];
  const float* ad0 = (const float*)d_in[4];
  const float* b0  = (const float*)d_in[5];
  const float* W1  = (const float*)d_in[6];
  const float* as1 = (const float*)d_in[7];
  const float* ad1 = (const float*)d_in[8];
  const float* b1  = (const float*)d_in[9];
  const float* W2  = (const float*)d_in[10];
  const float* as2 = (const float*)d_in[11];
  const float* ad2 = (const float*)d_in[12];
  const float* b2  = (const float*)d_in[13];
  int N = in_sizes[0] / 256;
  int E = in_sizes[1] / 2;
  int Etot = E + N;

  size_t off = 0;
  auto alc = [&](size_t bytes) -> char* {
    char* p = (char*)d_ws + off;
    off += (bytes + 255) & ~(size_t)255;
    return p;
  };
  ushort_t* xb    = (ushort_t*)alc((size_t)N * 256 * 2); // x bf16; later h1b,h2b
  ushort_t* h0b   = (ushort_t*)alc((size_t)N * 256 * 2); // h0 bf16; later g1b,g2b
  float*    als   = (float*)alc((size_t)N * 4 * 4);
  float*    ald   = (float*)alc((size_t)N * 4 * 4);
  int*      esrc  = (int*)alc((size_t)Etot * 4);
  int*      rowptr= (int*)alc((size_t)(N + 1) * 4);
  int*      cnt   = (int*)alc((size_t)N * 4);
  int*      cursor= (int*)alc((size_t)N * 4);
  int*      bsum  = (int*)alc(256 * 4);
  ushort_t* W0p   = (ushort_t*)alc(256 * 256 * 2);
  ushort_t* W1p   = (ushort_t*)alc(256 * 64 * 2);
  ushort_t* W2p   = (ushort_t*)alc(64 * 64 * 2);

  ushort_t* h1b = xb;                      // xb dead after GEMM0
  ushort_t* h2b = xb;                      // h1b dead after GEMM1
  ushort_t* g1b = h0b;                     // h0b dead after agg0
  ushort_t* g2b = h0b;                     // g1b dead after agg1-L1

  int nb = (N + 255) / 256;
  int eb = (Etot + 255) / 256;
  int fb = (N * 64 + 255) / 256;           // x->bf16 blocks (float4 granules)
  int rb = ((N / 16) + 7) / 8;             // 2 row-tiles/wave, 4 waves/block

  // ---- prep: hist + x->bf16 + weight transposes (one kernel) ----
  hipMemsetAsync(cnt, 0, (size_t)N * 4, stream);
  prep_kernel<<<eb + fb + 336, 256, 0, stream>>>(ei, cnt, (const float4*)x,
                                                 (ushort4*)xb, N * 64,
                                                 W0, W0p, W1, W1p, W2, W2p,
                                                 E, Etot, eb, fb);
  // ---- CSR scan + scatter ----
  blocksum_kernel<<<nb, 256, 0, stream>>>(cnt, bsum, N);
  scanb_kernel<<<1, 256, 0, stream>>>(bsum, nb);
  scan2_kernel<<<nb, 256, 0, stream>>>(cnt, bsum, rowptr, cursor, N, Etot);
  scatter_kernel<<<eb, 256, 0, stream>>>(ei, cursor, esrc, E, Etot);

  // ---- Layer 0: 256 -> 4x64 concat ----
  mfma_gemm<<<dim3(rb, 4), 256, 0, stream>>>(xb, W0p, h0b, as0, ad0,
                                             als, ald, N, 256, 256);
  agg0_kernel<<<N, 128, 0, stream>>>(rowptr, esrc, (const unsigned*)h0b,
                                     (const float4*)als, (const float4*)ald,
                                     b0, (unsigned*)h1b);

  // ---- Layer 1: 256 -> 64 ----
  mfma_gemm<<<dim3(rb, 1), 256, 0, stream>>>(h1b, W1p, g1b, as1, ad1,
                                             als, ald, N, 256, 64);
  agg1_kernel<0><<<(N + 3) / 4, 256, 0, stream>>>(rowptr, esrc, g1b, als, ald,
                                                  b1, h2b, N);

  // ---- Layer 2: 64 -> 64 ----
  mfma_gemm<<<dim3(rb, 1), 256, 0, stream>>>(h2b, W2p, g2b, as2, ad2,
                                             als, ald, N, 64, 64);
  agg1_kernel<1><<<(N + 3) / 4, 256, 0, stream>>>(rowptr, esrc, g2b, als, ald,
                                                  b2, d_out, N);
}

// Round 7
// 391.497 us; speedup vs baseline: 4.2350x; 1.1894x over previous
//
#include <hip/hip_runtime.h>
#include <hip/hip_bf16.h>

// ModifiedGAT, round 7: latency-tolerant aggregation.
//  Round-6 evidence: agg kernels are gather-miss-latency bound (static VALU
//  work ~7us vs 72us observed; FETCH = 8 XCDs x table size). Fix: fixed
//  16-iteration unrolled inner loops so ~16 independent gather loads are in
//  flight per wave; wave-per-node (agg0 uint2/lane, agg1 2 edges per wave via
//  half-wave split); shfl broadcast of per-edge softmax weights (no LDS, no
//  barriers -> safe with per-wave trip counts).

typedef unsigned short ushort_t;
typedef __attribute__((ext_vector_type(8))) short short8;
typedef __attribute__((ext_vector_type(4))) float f32x4;

__device__ __forceinline__ float elu_f(float x){ return x > 0.f ? x : expm1f(x); }
__device__ __forceinline__ float lrelu_f(float x){ return x > 0.f ? x : 0.2f * x; }
__device__ __forceinline__ ushort_t f2b(float f){
  union { float f; unsigned u; } v; v.f = f;
  unsigned r = v.u + 0x7fff + ((v.u >> 16) & 1);   // round-to-nearest-even
  return (ushort_t)(r >> 16);
}
__device__ __forceinline__ float b2f_lo(unsigned v){
  union { unsigned u; float f; } c; c.u = v << 16; return c.f;
}
__device__ __forceinline__ float b2f_hi(unsigned v){
  union { unsigned u; float f; } c; c.u = v & 0xffff0000u; return c.f;
}

// ---------------- fused prep: hist + x->bf16 + weight transposes -------------
__global__ __launch_bounds__(256) void prep_kernel(const int* __restrict__ ei,
                                                   int* __restrict__ cnt,
                                                   const float4* __restrict__ x4,
                                                   ushort4* __restrict__ xb4, int n4,
                                                   const float* __restrict__ W0,
                                                   ushort_t* __restrict__ W0p,
                                                   const float* __restrict__ W1,
                                                   ushort_t* __restrict__ W1p,
                                                   const float* __restrict__ W2,
                                                   ushort_t* __restrict__ W2p,
                                                   int E, int Etot, int eb, int fb){
  int bid = blockIdx.x; int t = threadIdx.x;
  if(bid < eb){
    int e = bid * 256 + t;
    if(e < Etot){
      int d = (e < E) ? ei[E + e] : (e - E);
      atomicAdd(&cnt[d], 1);
    }
  } else if(bid < eb + fb){
    int i = (bid - eb) * 256 + t;
    if(i < n4){
      float4 v = x4[i];
      ushort4 o;
      o.x = f2b(v.x); o.y = f2b(v.y); o.z = f2b(v.z); o.w = f2b(v.w);
      xb4[i] = o;
    }
  } else {
    int r = bid - eb - fb;
    if(r < 256){            // W0: 256x256
      int i = r * 256 + t; int k = i >> 8, n = i & 255;
      W0p[(size_t)n * 256 + k] = f2b(W0[i]);
    } else if(r < 320){     // W1: 256x64
      int i = (r - 256) * 256 + t; int k = i >> 6, n = i & 63;
      W1p[(size_t)n * 256 + k] = f2b(W1[i]);
    } else {                // W2: 64x64
      int i = (r - 320) * 256 + t; int k = i >> 6, n = i & 63;
      W2p[(size_t)n * 64 + k] = f2b(W2[i]);
    }
  }
}

// ---------------- MFMA GEMM: C[M,NC] = A[M,K] @ B[K,NC], 2 row-tiles/wave ---
__global__ __launch_bounds__(256) void mfma_gemm(const ushort_t* __restrict__ A,
                                                 const ushort_t* __restrict__ Bp,
                                                 ushort_t* __restrict__ Cp,
                                                 const float* __restrict__ asrc,
                                                 const float* __restrict__ adst,
                                                 float* __restrict__ als,
                                                 float* __restrict__ ald,
                                                 int M, int K, int NC){
  int wave = threadIdx.x >> 6;
  int lane = threadIdx.x & 63;
  int tile0 = (blockIdx.x * 4 + wave) * 2;   // first 16-row tile (M%16==0)
  if(tile0 * 16 >= M) return;
  bool two = (tile0 + 1) * 16 < M;
  int colb = blockIdx.y;
  int m = lane & 15, q = lane >> 4;
  const ushort_t* Ab = A + (size_t)(tile0 * 16 + m) * K + q * 8;
  const ushort_t* Bq = Bp + (size_t)(colb * 64 + m) * K + q * 8;
  f32x4 acc[2][4] = {};
  for(int k0 = 0; k0 < K; k0 += 32){
    short8 bv[4];
    #pragma unroll
    for(int j = 0; j < 4; j++) bv[j] = *(const short8*)(Bq + (size_t)j * 16 * K + k0);
    short8 a0 = *(const short8*)(Ab + k0);
    #pragma unroll
    for(int j = 0; j < 4; j++)
      acc[0][j] = __builtin_amdgcn_mfma_f32_16x16x32_bf16(a0, bv[j], acc[0][j], 0, 0, 0);
    if(two){
      short8 a1 = *(const short8*)(Ab + (size_t)16 * K + k0);
      #pragma unroll
      for(int j = 0; j < 4; j++)
        acc[1][j] = __builtin_amdgcn_mfma_f32_16x16x32_bf16(a1, bv[j], acc[1][j], 0, 0, 0);
    }
  }
  int hstride = gridDim.y;
  #pragma unroll
  for(int r = 0; r < 2; r++){
    if(r == 1 && !two) break;
    int rowt = tile0 + r;
    #pragma unroll
    for(int j = 0; j < 4; j++){
      int col = colb * 64 + j * 16 + m;
      #pragma unroll
      for(int i = 0; i < 4; i++){
        int rr = rowt * 16 + q * 4 + i;
        Cp[(size_t)rr * NC + col] = f2b(acc[r][j][i]);
      }
    }
    float vs[4] = {0,0,0,0}, vd[4] = {0,0,0,0};
    #pragma unroll
    for(int j = 0; j < 4; j++){
      int col = colb * 64 + j * 16 + m;
      float a_s = asrc[col], a_d = adst[col];
      #pragma unroll
      for(int i = 0; i < 4; i++){
        vs[i] = fmaf(acc[r][j][i], a_s, vs[i]);
        vd[i] = fmaf(acc[r][j][i], a_d, vd[i]);
      }
    }
    #pragma unroll
    for(int off = 8; off > 0; off >>= 1){
      #pragma unroll
      for(int i = 0; i < 4; i++){
        vs[i] += __shfl_down(vs[i], off, 16);
        vd[i] += __shfl_down(vd[i], off, 16);
      }
    }
    if(m == 0){
      #pragma unroll
      for(int i = 0; i < 4; i++){
        int rr = rowt * 16 + q * 4 + i;
        als[(size_t)rr * hstride + colb] = vs[i];
        ald[(size_t)rr * hstride + colb] = vd[i];
      }
    }
  }
}

// ---------------- CSR build ---------------------------------------------------
__global__ __launch_bounds__(256) void blocksum_kernel(const int* __restrict__ cnt,
                                                       int* __restrict__ bsum, int N){
  __shared__ int sm[256];
  int t = threadIdx.x;
  int i = blockIdx.x * 256 + t;
  sm[t] = (i < N) ? cnt[i] : 0;
  __syncthreads();
  for(int off = 128; off > 0; off >>= 1){
    if(t < off) sm[t] += sm[t + off];
    __syncthreads();
  }
  if(t == 0) bsum[blockIdx.x] = sm[0];
}

__global__ __launch_bounds__(256) void scanb_kernel(int* __restrict__ bsum, int nb){
  __shared__ int sm[256];
  int t = threadIdx.x;
  int v = (t < nb) ? bsum[t] : 0;
  sm[t] = v;
  __syncthreads();
  for(int off = 1; off < 256; off <<= 1){
    int x = 0;
    if(t >= off) x = sm[t - off];
    __syncthreads();
    sm[t] += x;
    __syncthreads();
  }
  if(t < nb) bsum[t] = sm[t] - v;   // exclusive
}

__global__ __launch_bounds__(256) void scan2_kernel(const int* __restrict__ cnt,
                                                    const int* __restrict__ bsum,
                                                    int* __restrict__ rowptr,
                                                    int* __restrict__ cursor,
                                                    int N, int Etot){
  __shared__ int sm[256];
  int t = threadIdx.x;
  int i = blockIdx.x * 256 + t;
  int v = (i < N) ? cnt[i] : 0;
  sm[t] = v;
  __syncthreads();
  for(int off = 1; off < 256; off <<= 1){
    int x = 0;
    if(t >= off) x = sm[t - off];
    __syncthreads();
    sm[t] += x;
    __syncthreads();
  }
  if(i < N){
    int ex = sm[t] - v + bsum[blockIdx.x];
    rowptr[i] = ex;
    cursor[i] = ex;
    if(i == N - 1) rowptr[N] = Etot;
  }
}

__global__ __launch_bounds__(256) void scatter_kernel(const int* __restrict__ ei,
                                                      int* __restrict__ cursor,
                                                      int* __restrict__ esrc,
                                                      int E, int Etot){
  int e = blockIdx.x * 256 + threadIdx.x;
  if(e >= Etot) return;
  int s, d;
  if(e < E){ s = ei[e]; d = ei[E + e]; } else { s = e - E; d = s; }
  int pos = atomicAdd(&cursor[d], 1);
  esrc[pos] = s;
}

// ---------------- agg layer0: wave per node, uint2 (4 feats) per lane --------
// Chunk = 16 edges. Lane L computes the softmax weight of edge (L&15) for
// head (L>>4); inner loop broadcasts via shfl with lane-computable index.
// Fixed trip count -> fully unrolled -> 16 gather loads in flight.
__global__ __launch_bounds__(256) void agg0_kernel(const int* __restrict__ rowptr,
                                                   const int* __restrict__ esrc,
                                                   const uint2* __restrict__ h0b2,
                                                   const float4* __restrict__ als4,
                                                   const float4* __restrict__ ald4,
                                                   const float4* __restrict__ b4,
                                                   uint2* __restrict__ out2, int N){
  int t = threadIdx.x;
  int lane = t & 63;
  int n = blockIdx.x * 4 + (t >> 6);
  if(n >= N) return;
  int h = lane >> 4;                        // head of this lane's 4 features
  int beg = rowptr[n], end = rowptr[n + 1];
  float adh = ((const float*)(ald4 + n))[h];
  float4 acc = make_float4(0.f, 0.f, 0.f, 0.f);
  float den = 0.f;
  for(int c0 = beg; c0 < end; c0 += 16){
    int e = c0 + (lane & 15);
    int s = n; float w = 0.f;
    if(e < end){
      s = esrc[e];
      w = expf(lrelu_f(((const float*)(als4 + s))[h] + adh));
    }
    #pragma unroll
    for(int i = 0; i < 16; i++){
      int idx = (lane & 48) + i;
      int si = __shfl(s, idx, 64);
      float wi = __shfl(w, idx, 64);
      uint2 v = h0b2[((size_t)si << 6) + lane];
      acc.x = fmaf(wi, b2f_lo(v.x), acc.x);
      acc.y = fmaf(wi, b2f_hi(v.x), acc.y);
      acc.z = fmaf(wi, b2f_lo(v.y), acc.z);
      acc.w = fmaf(wi, b2f_hi(v.y), acc.w);
      den += wi;
    }
  }
  float inv = 1.f / (den + 1e-16f);
  float4 bb = b4[lane];
  float v0 = elu_f(acc.x * inv + bb.x);
  float v1 = elu_f(acc.y * inv + bb.y);
  float v2 = elu_f(acc.z * inv + bb.z);
  float v3 = elu_f(acc.w * inv + bb.w);
  uint2 o;
  o.x = (unsigned)f2b(v0) | ((unsigned)f2b(v1) << 16);
  o.y = (unsigned)f2b(v2) | ((unsigned)f2b(v3) << 16);
  out2[((size_t)n << 6) + lane] = o;
}

// ---------------- agg layers 1/2: wave per node, 2 edges/iteration -----------
// Half-wave h=lane>>5 processes edges 2i+h; lane covers feature pair lane&31
// via one uint load. Chunk = 32 edges, fixed 16-iteration unrolled body.
// Final cross-half combine via shfl_xor(32). OMODE 0: bf16 out, 1: fp32 out.
template<int OMODE>
__global__ __launch_bounds__(256) void agg1_kernel(const int* __restrict__ rowptr,
                                                   const int* __restrict__ esrc,
                                                   const unsigned* __restrict__ gb,
                                                   const float* __restrict__ als,
                                                   const float* __restrict__ ald,
                                                   const float* __restrict__ b,
                                                   void* __restrict__ outp, int N){
  int t = threadIdx.x;
  int lane = t & 63;
  int n = blockIdx.x * 4 + (t >> 6);
  if(n >= N) return;
  int half = lane >> 5;
  int p = lane & 31;                        // feature pair index
  int beg = rowptr[n], end = rowptr[n + 1];
  float ad = ald[n];
  float a0 = 0.f, a1 = 0.f, den = 0.f;
  for(int c0 = beg; c0 < end; c0 += 32){
    int e = c0 + p;                         // both halves duplicate edge p
    int s = n; float w = 0.f;
    if(e < end){
      s = esrc[e];
      w = expf(lrelu_f(als[s] + ad));
    }
    #pragma unroll
    for(int i = 0; i < 16; i++){
      int idx = 2 * i + half;
      int si = __shfl(s, idx, 64);
      float wi = __shfl(w, idx, 64);
      unsigned v = gb[((size_t)si << 5) + p];
      a0 = fmaf(wi, b2f_lo(v), a0);
      a1 = fmaf(wi, b2f_hi(v), a1);
      den += wi;
    }
  }
  a0 += __shfl_xor(a0, 32, 64);
  a1 += __shfl_xor(a1, 32, 64);
  den += __shfl_xor(den, 32, 64);
  float inv = 1.f / (den + 1e-16f);
  float2 bb = ((const float2*)b)[p];
  float v0 = elu_f(a0 * inv + bb.x);
  float v1 = elu_f(a1 * inv + bb.y);
  if(half == 0){
    if(OMODE == 0){
      ((unsigned*)outp)[((size_t)n << 5) + p] =
          (unsigned)f2b(v0) | ((unsigned)f2b(v1) << 16);
    } else {
      float2 o; o.x = v0; o.y = v1;
      ((float2*)outp)[((size_t)n << 5) + p] = o;
    }
  }
}

extern "C" void kernel_launch(void* const* d_in, const int* in_sizes, int n_in,
                              void* d_out, int out_size, void* d_ws, size_t ws_size,
                              hipStream_t stream){
  const float* x   = (const float*)d_in[0];
  const int*   ei  = (const int*)d_in[1];
  const float* W0  = (const float*)d_in[2];
  const float* as0 = (const float*)d_in[3];
  const float* ad0 = (const float*)d_in[4];
  const float* b0  = (const float*)d_in[5];
  const float* W1  = (const float*)d_in[6];
  const float* as1 = (const float*)d_in[7];
  const float* ad1 = (const float*)d_in[8];
  const float* b1  = (const float*)d_in[9];
  const float* W2  = (const float*)d_in[10];
  const float* as2 = (const float*)d_in[11];
  const float* ad2 = (const float*)d_in[12];
  const float* b2  = (const float*)d_in[13];
  int N = in_sizes[0] / 256;
  int E = in_sizes[1] / 2;
  int Etot = E + N;

  size_t off = 0;
  auto alc = [&](size_t bytes) -> char* {
    char* p = (char*)d_ws + off;
    off += (bytes + 255) & ~(size_t)255;
    return p;
  };
  ushort_t* xb    = (ushort_t*)alc((size_t)N * 256 * 2); // x bf16; later h1b,h2b
  ushort_t* h0b   = (ushort_t*)alc((size_t)N * 256 * 2); // h0 bf16; later g1b,g2b
  float*    als   = (float*)alc((size_t)N * 4 * 4);
  float*    ald   = (float*)alc((size_t)N * 4 * 4);
  int*      esrc  = (int*)alc((size_t)Etot * 4);
  int*      rowptr= (int*)alc((size_t)(N + 1) * 4);
  int*      cnt   = (int*)alc((size_t)N * 4);
  int*      cursor= (int*)alc((size_t)N * 4);
  int*      bsum  = (int*)alc(256 * 4);
  ushort_t* W0p   = (ushort_t*)alc(256 * 256 * 2);
  ushort_t* W1p   = (ushort_t*)alc(256 * 64 * 2);
  ushort_t* W2p   = (ushort_t*)alc(64 * 64 * 2);

  ushort_t* h1b = xb;                      // xb dead after GEMM0
  ushort_t* h2b = xb;                      // h1b dead after GEMM1
  ushort_t* g1b = h0b;                     // h0b dead after agg0
  ushort_t* g2b = h0b;                     // g1b dead after agg1-L1

  int nb = (N + 255) / 256;
  int eb = (Etot + 255) / 256;
  int fb = (N * 64 + 255) / 256;           // x->bf16 blocks (float4 granules)
  int rb = ((N / 16) + 7) / 8;             // 2 row-tiles/wave, 4 waves/block
  int ab = (N + 3) / 4;                    // agg blocks (4 nodes each)

  // ---- prep: hist + x->bf16 + weight transposes (one kernel) ----
  hipMemsetAsync(cnt, 0, (size_t)N * 4, stream);
  prep_kernel<<<eb + fb + 336, 256, 0, stream>>>(ei, cnt, (const float4*)x,
                                                 (ushort4*)xb, N * 64,
                                                 W0, W0p, W1, W1p, W2, W2p,
                                                 E, Etot, eb, fb);
  // ---- CSR scan + scatter ----
  blocksum_kernel<<<nb, 256, 0, stream>>>(cnt, bsum, N);
  scanb_kernel<<<1, 256, 0, stream>>>(bsum, nb);
  scan2_kernel<<<nb, 256, 0, stream>>>(cnt, bsum, rowptr, cursor, N, Etot);
  scatter_kernel<<<eb, 256, 0, stream>>>(ei, cursor, esrc, E, Etot);

  // ---- Layer 0: 256 -> 4x64 concat ----
  mfma_gemm<<<dim3(rb, 4), 256, 0, stream>>>(xb, W0p, h0b, as0, ad0,
                                             als, ald, N, 256, 256);
  agg0_kernel<<<ab, 256, 0, stream>>>(rowptr, esrc, (const uint2*)h0b,
                                      (const float4*)als, (const float4*)ald,
                                      (const float4*)b0, (uint2*)h1b, N);

  // ---- Layer 1: 256 -> 64 ----
  mfma_gemm<<<dim3(rb, 1), 256, 0, stream>>>(h1b, W1p, g1b, as1, ad1,
                                             als, ald, N, 256, 64);
  agg1_kernel<0><<<ab, 256, 0, stream>>>(rowptr, esrc, (const unsigned*)g1b,
                                         als, ald, b1, h2b, N);

  // ---- Layer 2: 64 -> 64 ----
  mfma_gemm<<<dim3(rb, 1), 256, 0, stream>>>(h2b, W2p, g2b, as2, ad2,
                                             als, ald, N, 64, 64);
  agg1_kernel<1><<<ab, 256, 0, stream>>>(rowptr, esrc, (const unsigned*)g2b,
                                         als, ald, b2, d_out, N);
}

// Round 9
// 379.163 us; speedup vs baseline: 4.3728x; 1.0325x over previous
//
#include <hip/hip_runtime.h>
#include <hip/hip_bf16.h>

// ModifiedGAT, round 9:
//  - fp8 REVERTED (round-8 absmax 0.0234 > 0.0138: e4m3's 6% worst-case rel
//    error lands raw on softmax-dominated nodes; gather tables must be bf16).
//  - GEMM0 keeps round-8's LDS A-staging (validated structurally), bf16 out.
//  - GEMM1 fused into agg0 (block = 16 nodes, LDS h1 tile, MFMA from LDS):
//    h1 never hits HBM. GEMM2 fused into agg1-L1 the same way.
//  - layers: gemm0 -> agg0g1 -> agg1g2 -> agg1(final, fp32 out).

typedef unsigned short ushort_t;
typedef __attribute__((ext_vector_type(8))) short short8;
typedef __attribute__((ext_vector_type(4))) float f32x4;

__device__ __forceinline__ float elu_f(float x){ return x > 0.f ? x : expm1f(x); }
__device__ __forceinline__ float lrelu_f(float x){ return x > 0.f ? x : 0.2f * x; }
__device__ __forceinline__ ushort_t f2b(float f){
  union { float f; unsigned u; } v; v.f = f;
  unsigned r = v.u + 0x7fff + ((v.u >> 16) & 1);   // round-to-nearest-even
  return (ushort_t)(r >> 16);
}
__device__ __forceinline__ float b2f_lo(unsigned v){
  union { unsigned u; float f; } c; c.u = v << 16; return c.f;
}
__device__ __forceinline__ float b2f_hi(unsigned v){
  union { unsigned u; float f; } c; c.u = v & 0xffff0000u; return c.f;
}

// ---------------- fused prep: hist + x->bf16 + weight transposes -------------
__global__ __launch_bounds__(256) void prep_kernel(const int* __restrict__ ei,
                                                   int* __restrict__ cnt,
                                                   const float4* __restrict__ x4,
                                                   ushort4* __restrict__ xb4, int n4,
                                                   const float* __restrict__ W0,
                                                   ushort_t* __restrict__ W0p,
                                                   const float* __restrict__ W1,
                                                   ushort_t* __restrict__ W1p,
                                                   const float* __restrict__ W2,
                                                   ushort_t* __restrict__ W2p,
                                                   int E, int Etot, int eb, int fb){
  int bid = blockIdx.x; int t = threadIdx.x;
  if(bid < eb){
    int e = bid * 256 + t;
    if(e < Etot){
      int d = (e < E) ? ei[E + e] : (e - E);
      atomicAdd(&cnt[d], 1);
    }
  } else if(bid < eb + fb){
    int i = (bid - eb) * 256 + t;
    if(i < n4){
      float4 v = x4[i];
      ushort4 o;
      o.x = f2b(v.x); o.y = f2b(v.y); o.z = f2b(v.z); o.w = f2b(v.w);
      xb4[i] = o;
    }
  } else {
    int r = bid - eb - fb;
    if(r < 256){            // W0: 256x256
      int i = r * 256 + t; int k = i >> 8, n = i & 255;
      W0p[(size_t)n * 256 + k] = f2b(W0[i]);
    } else if(r < 320){     // W1: 256x64
      int i = (r - 256) * 256 + t; int k = i >> 6, n = i & 63;
      W1p[(size_t)n * 256 + k] = f2b(W1[i]);
    } else {                // W2: 64x64
      int i = (r - 320) * 256 + t; int k = i >> 6, n = i & 63;
      W2p[(size_t)n * 64 + k] = f2b(W2[i]);
    }
  }
}

// ---------------- GEMM0: h0b[M,256] = bf16(x[M,256] @ W0) + logits ----------
#define SKP 264   // padded LDS k-stride (shorts)
__global__ __launch_bounds__(256) void gemm0_kernel(const ushort_t* __restrict__ A,
                                                    const ushort_t* __restrict__ Bp,
                                                    ushort_t* __restrict__ h0b,
                                                    const float* __restrict__ asrc,
                                                    const float* __restrict__ adst,
                                                    float* __restrict__ als,
                                                    float* __restrict__ ald, int M){
  __shared__ ushort_t As[32 * SKP];
  int t = threadIdx.x;
  int row0 = blockIdx.x * 32;
  {
    int c = t;                       // 1024 16B-chunks: 32 rows x 32 chunks
    #pragma unroll
    for(int it = 0; it < 4; it++, c += 256){
      int r = c >> 5;
      int kc = (c & 31) << 3;
      int gr = row0 + r;
      short8 v = {};
      if(gr < M) v = *(const short8*)(A + (size_t)gr * 256 + kc);
      *(short8*)(As + r * SKP + kc) = v;
    }
  }
  __syncthreads();
  int wave = t >> 6, lane = t & 63;
  int m = lane & 15, q = lane >> 4;
  int colb = wave;                   // head
  const ushort_t* Bq = Bp + (size_t)(colb * 64 + m) * 256 + q * 8;
  const ushort_t* A0 = As + m * SKP + q * 8;
  const ushort_t* A1 = As + (16 + m) * SKP + q * 8;
  f32x4 acc[2][4] = {};
  for(int k0 = 0; k0 < 256; k0 += 32){
    short8 bv[4];
    #pragma unroll
    for(int j = 0; j < 4; j++) bv[j] = *(const short8*)(Bq + (size_t)j * 16 * 256 + k0);
    short8 a0 = *(const short8*)(A0 + k0);
    short8 a1 = *(const short8*)(A1 + k0);
    #pragma unroll
    for(int j = 0; j < 4; j++){
      acc[0][j] = __builtin_amdgcn_mfma_f32_16x16x32_bf16(a0, bv[j], acc[0][j], 0, 0, 0);
      acc[1][j] = __builtin_amdgcn_mfma_f32_16x16x32_bf16(a1, bv[j], acc[1][j], 0, 0, 0);
    }
  }
  #pragma unroll
  for(int rt = 0; rt < 2; rt++){
    #pragma unroll
    for(int j = 0; j < 4; j++){
      int col = colb * 64 + j * 16 + m;
      #pragma unroll
      for(int i = 0; i < 4; i++){
        int gr = row0 + rt * 16 + q * 4 + i;
        if(gr < M) h0b[(size_t)gr * 256 + col] = f2b(acc[rt][j][i]);
      }
    }
    float vs[4] = {0,0,0,0}, vd[4] = {0,0,0,0};
    #pragma unroll
    for(int j = 0; j < 4; j++){
      int col = colb * 64 + j * 16 + m;
      float a_s = asrc[col], a_d = adst[col];
      #pragma unroll
      for(int i = 0; i < 4; i++){
        vs[i] = fmaf(acc[rt][j][i], a_s, vs[i]);
        vd[i] = fmaf(acc[rt][j][i], a_d, vd[i]);
      }
    }
    #pragma unroll
    for(int off = 8; off > 0; off >>= 1){
      #pragma unroll
      for(int i = 0; i < 4; i++){
        vs[i] += __shfl_down(vs[i], off, 16);
        vd[i] += __shfl_down(vd[i], off, 16);
      }
    }
    if(m == 0){
      #pragma unroll
      for(int i = 0; i < 4; i++){
        int gr = row0 + rt * 16 + q * 4 + i;
        if(gr < M){
          als[(size_t)gr * 4 + colb] = vs[i];
          ald[(size_t)gr * 4 + colb] = vd[i];
        }
      }
    }
  }
}

// ---------------- CSR build ---------------------------------------------------
__global__ __launch_bounds__(256) void blocksum_kernel(const int* __restrict__ cnt,
                                                       int* __restrict__ bsum, int N){
  __shared__ int sm[256];
  int t = threadIdx.x;
  int i = blockIdx.x * 256 + t;
  sm[t] = (i < N) ? cnt[i] : 0;
  __syncthreads();
  for(int off = 128; off > 0; off >>= 1){
    if(t < off) sm[t] += sm[t + off];
    __syncthreads();
  }
  if(t == 0) bsum[blockIdx.x] = sm[0];
}

__global__ __launch_bounds__(256) void scanb_kernel(int* __restrict__ bsum, int nb){
  __shared__ int sm[256];
  int t = threadIdx.x;
  int v = (t < nb) ? bsum[t] : 0;
  sm[t] = v;
  __syncthreads();
  for(int off = 1; off < 256; off <<= 1){
    int x = 0;
    if(t >= off) x = sm[t - off];
    __syncthreads();
    sm[t] += x;
    __syncthreads();
  }
  if(t < nb) bsum[t] = sm[t] - v;   // exclusive
}

__global__ __launch_bounds__(256) void scan2_kernel(const int* __restrict__ cnt,
                                                    const int* __restrict__ bsum,
                                                    int* __restrict__ rowptr,
                                                    int* __restrict__ cursor,
                                                    int N, int Etot){
  __shared__ int sm[256];
  int t = threadIdx.x;
  int i = blockIdx.x * 256 + t;
  int v = (i < N) ? cnt[i] : 0;
  sm[t] = v;
  __syncthreads();
  for(int off = 1; off < 256; off <<= 1){
    int x = 0;
    if(t >= off) x = sm[t - off];
    __syncthreads();
    sm[t] += x;
    __syncthreads();
  }
  if(i < N){
    int ex = sm[t] - v + bsum[blockIdx.x];
    rowptr[i] = ex;
    cursor[i] = ex;
    if(i == N - 1) rowptr[N] = Etot;
  }
}

__global__ __launch_bounds__(256) void scatter_kernel(const int* __restrict__ ei,
                                                      int* __restrict__ cursor,
                                                      int* __restrict__ esrc,
                                                      int E, int Etot){
  int e = blockIdx.x * 256 + threadIdx.x;
  if(e >= Etot) return;
  int s, d;
  if(e < E){ s = ei[e]; d = ei[E + e]; } else { s = e - E; d = s; }
  int pos = atomicAdd(&cursor[d], 1);
  esrc[pos] = s;
}

// ---------------- agg0 + GEMM1 fused -----------------------------------------
// Block = 16 nodes, 4 waves. Phase 1: wave aggregates 4 nodes (round-7 loop,
// uint2 bf16 gather, shfl weight broadcast), ELU'd h1 row -> LDS tile.
// Phase 2: wave w computes g1 cols [16w,16w+16) via 8 MFMAs from LDS; writes
// bf16 g1b + layer-1 logit partials (reduced across waves in LDS).
#define H1S 264   // LDS h1 tile k-stride (shorts): 528B rows, 16B aligned
__global__ __launch_bounds__(256) void agg0g1_kernel(const int* __restrict__ rowptr,
                                                     const int* __restrict__ esrc,
                                                     const uint2* __restrict__ h0b2,
                                                     const float* __restrict__ als,
                                                     const float* __restrict__ ald,
                                                     const float* __restrict__ b0,
                                                     const ushort_t* __restrict__ W1p,
                                                     const float* __restrict__ as1,
                                                     const float* __restrict__ ad1,
                                                     ushort_t* __restrict__ g1b,
                                                     float* __restrict__ als1,
                                                     float* __restrict__ ald1, int N){
  __shared__ ushort_t Hs[16 * H1S];
  __shared__ float aps[4][16], apd[4][16];
  int t = threadIdx.x;
  int wave = t >> 6, lane = t & 63;
  int nbase = blockIdx.x * 16;
  int h = lane >> 4;
  int mm16 = lane & 15;
  // ---- phase 1: aggregate 4 nodes per wave ----
  for(int j = 0; j < 4; j++){
    int n = nbase + wave * 4 + j;
    int nl = wave * 4 + j;
    if(n < N){
      int beg = rowptr[n], end = rowptr[n + 1];
      float adh = ald[(size_t)n * 4 + h];
      float4 acc = make_float4(0.f, 0.f, 0.f, 0.f);
      float den = 0.f;
      for(int c0 = beg; c0 < end; c0 += 16){
        int e = c0 + mm16;
        int s = n; float w = 0.f;
        if(e < end){
          s = esrc[e];
          w = expf(lrelu_f(als[(size_t)s * 4 + h] + adh));
        }
        #pragma unroll
        for(int i = 0; i < 16; i++){
          int idx = (lane & 48) + i;
          int si = __shfl(s, idx, 64);
          float wi = __shfl(w, idx, 64);
          uint2 v = h0b2[((size_t)si << 6) + lane];
          acc.x = fmaf(wi, b2f_lo(v.x), acc.x);
          acc.y = fmaf(wi, b2f_hi(v.x), acc.y);
          acc.z = fmaf(wi, b2f_lo(v.y), acc.z);
          acc.w = fmaf(wi, b2f_hi(v.y), acc.w);
          den += wi;
        }
      }
      float inv = 1.f / (den + 1e-16f);
      float4 bb = ((const float4*)b0)[lane];
      uint2 o;
      o.x = (unsigned)f2b(elu_f(acc.x * inv + bb.x)) |
            ((unsigned)f2b(elu_f(acc.y * inv + bb.y)) << 16);
      o.y = (unsigned)f2b(elu_f(acc.z * inv + bb.z)) |
            ((unsigned)f2b(elu_f(acc.w * inv + bb.w)) << 16);
      *(uint2*)(Hs + nl * H1S + lane * 4) = o;   // feats 4*lane..4*lane+3
    }
  }
  __syncthreads();
  // ---- phase 2: g1 tile (16 nodes x 64 cols), wave w = cols [16w,16w+16) ----
  int m = lane & 15, q = lane >> 4;
  const ushort_t* Bw = W1p + (size_t)(wave * 16 + m) * 256 + q * 8;
  const ushort_t* Aw = Hs + m * H1S + q * 8;
  f32x4 acc = {};
  #pragma unroll
  for(int k0 = 0; k0 < 256; k0 += 32){
    short8 av = *(const short8*)(Aw + k0);
    short8 bv = *(const short8*)(Bw + k0);
    acc = __builtin_amdgcn_mfma_f32_16x16x32_bf16(av, bv, acc, 0, 0, 0);
  }
  float a_s = as1[wave * 16 + m], a_d = ad1[wave * 16 + m];
  float vs[4], vd[4];
  #pragma unroll
  for(int i = 0; i < 4; i++){
    int gn = nbase + q * 4 + i;
    if(gn < N) g1b[(size_t)gn * 64 + wave * 16 + m] = f2b(acc[i]);
    vs[i] = acc[i] * a_s;
    vd[i] = acc[i] * a_d;
  }
  #pragma unroll
  for(int off = 8; off > 0; off >>= 1){
    #pragma unroll
    for(int i = 0; i < 4; i++){
      vs[i] += __shfl_down(vs[i], off, 16);
      vd[i] += __shfl_down(vd[i], off, 16);
    }
  }
  if(m == 0){
    #pragma unroll
    for(int i = 0; i < 4; i++){
      aps[wave][q * 4 + i] = vs[i];
      apd[wave][q * 4 + i] = vd[i];
    }
  }
  __syncthreads();
  if(t < 16){
    int gn = nbase + t;
    if(gn < N){
      als1[gn] = aps[0][t] + aps[1][t] + aps[2][t] + aps[3][t];
      ald1[gn] = apd[0][t] + apd[1][t] + apd[2][t] + apd[3][t];
    }
  }
}

// ---------------- agg1-L1 + GEMM2 fused --------------------------------------
// Same structure; 64-dim rows, K=64 (2 MFMAs).
#define H2S 72    // LDS h2 tile k-stride (shorts): 144B rows
__global__ __launch_bounds__(256) void agg1g2_kernel(const int* __restrict__ rowptr,
                                                     const int* __restrict__ esrc,
                                                     const unsigned* __restrict__ g1b,
                                                     const float* __restrict__ als1,
                                                     const float* __restrict__ ald1,
                                                     const float* __restrict__ b1,
                                                     const ushort_t* __restrict__ W2p,
                                                     const float* __restrict__ as2,
                                                     const float* __restrict__ ad2,
                                                     ushort_t* __restrict__ g2b,
                                                     float* __restrict__ als2,
                                                     float* __restrict__ ald2, int N){
  __shared__ ushort_t Hs[16 * H2S];
  __shared__ float aps[4][16], apd[4][16];
  int t = threadIdx.x;
  int wave = t >> 6, lane = t & 63;
  int nbase = blockIdx.x * 16;
  int half = lane >> 5;
  int p = lane & 31;
  // ---- phase 1: aggregate 4 nodes per wave ----
  for(int j = 0; j < 4; j++){
    int n = nbase + wave * 4 + j;
    int nl = wave * 4 + j;
    if(n < N){
      int beg = rowptr[n], end = rowptr[n + 1];
      float ad = ald1[n];
      float a0 = 0.f, a1 = 0.f, den = 0.f;
      for(int c0 = beg; c0 < end; c0 += 32){
        int e = c0 + p;
        int s = n; float w = 0.f;
        if(e < end){
          s = esrc[e];
          w = expf(lrelu_f(als1[s] + ad));
        }
        #pragma unroll
        for(int i = 0; i < 16; i++){
          int idx = 2 * i + half;
          int si = __shfl(s, idx, 64);
          float wi = __shfl(w, idx, 64);
          unsigned v = g1b[((size_t)si << 5) + p];
          a0 = fmaf(wi, b2f_lo(v), a0);
          a1 = fmaf(wi, b2f_hi(v), a1);
          den += wi;
        }
      }
      a0 += __shfl_xor(a0, 32, 64);
      a1 += __shfl_xor(a1, 32, 64);
      den += __shfl_xor(den, 32, 64);
      float inv = 1.f / (den + 1e-16f);
      float2 bb = ((const float2*)b1)[p];
      if(half == 0){
        unsigned o = (unsigned)f2b(elu_f(a0 * inv + bb.x)) |
                     ((unsigned)f2b(elu_f(a1 * inv + bb.y)) << 16);
        *(unsigned*)(Hs + nl * H2S + p * 2) = o;   // feats 2p, 2p+1
      }
    }
  }
  __syncthreads();
  // ---- phase 2: g2 tile, wave w = cols [16w,16w+16), K=64 ----
  int m = lane & 15, q = lane >> 4;
  const ushort_t* Bw = W2p + (size_t)(wave * 16 + m) * 64 + q * 8;
  const ushort_t* Aw = Hs + m * H2S + q * 8;
  f32x4 acc = {};
  #pragma unroll
  for(int k0 = 0; k0 < 64; k0 += 32){
    short8 av = *(const short8*)(Aw + k0);
    short8 bv = *(const short8*)(Bw + k0);
    acc = __builtin_amdgcn_mfma_f32_16x16x32_bf16(av, bv, acc, 0, 0, 0);
  }
  float a_s = as2[wave * 16 + m], a_d = ad2[wave * 16 + m];
  float vs[4], vd[4];
  #pragma unroll
  for(int i = 0; i < 4; i++){
    int gn = nbase + q * 4 + i;
    if(gn < N) g2b[(size_t)gn * 64 + wave * 16 + m] = f2b(acc[i]);
    vs[i] = acc[i] * a_s;
    vd[i] = acc[i] * a_d;
  }
  #pragma unroll
  for(int off = 8; off > 0; off >>= 1){
    #pragma unroll
    for(int i = 0; i < 4; i++){
      vs[i] += __shfl_down(vs[i], off, 16);
      vd[i] += __shfl_down(vd[i], off, 16);
    }
  }
  if(m == 0){
    #pragma unroll
    for(int i = 0; i < 4; i++){
      aps[wave][q * 4 + i] = vs[i];
      apd[wave][q * 4 + i] = vd[i];
    }
  }
  __syncthreads();
  if(t < 16){
    int gn = nbase + t;
    if(gn < N){
      als2[gn] = aps[0][t] + aps[1][t] + aps[2][t] + aps[3][t];
      ald2[gn] = apd[0][t] + apd[1][t] + apd[2][t] + apd[3][t];
    }
  }
}

// ---------------- final agg (layer 2): wave per node, fp32 out ---------------
__global__ __launch_bounds__(256) void aggF_kernel(const int* __restrict__ rowptr,
                                                   const int* __restrict__ esrc,
                                                   const unsigned* __restrict__ gb,
                                                   const float* __restrict__ als,
                                                   const float* __restrict__ ald,
                                                   const float* __restrict__ b,
                                                   float2* __restrict__ outp, int N){
  int t = threadIdx.x;
  int lane = t & 63;
  int n = blockIdx.x * 4 + (t >> 6);
  if(n >= N) return;
  int half = lane >> 5;
  int p = lane & 31;
  int beg = rowptr[n], end = rowptr[n + 1];
  float ad = ald[n];
  float a0 = 0.f, a1 = 0.f, den = 0.f;
  for(int c0 = beg; c0 < end; c0 += 32){
    int e = c0 + p;
    int s = n; float w = 0.f;
    if(e < end){
      s = esrc[e];
      w = expf(lrelu_f(als[s] + ad));
    }
    #pragma unroll
    for(int i = 0; i < 16; i++){
      int idx = 2 * i + half;
      int si = __shfl(s, idx, 64);
      float wi = __shfl(w, idx, 64);
      unsigned v = gb[((size_t)si << 5) + p];
      a0 = fmaf(wi, b2f_lo(v), a0);
      a1 = fmaf(wi, b2f_hi(v), a1);
      den += wi;
    }
  }
  a0 += __shfl_xor(a0, 32, 64);
  a1 += __shfl_xor(a1, 32, 64);
  den += __shfl_xor(den, 32, 64);
  float inv = 1.f / (den + 1e-16f);
  float2 bb = ((const float2*)b)[p];
  if(half == 0){
    float2 o;
    o.x = elu_f(a0 * inv + bb.x);
    o.y = elu_f(a1 * inv + bb.y);
    outp[((size_t)n << 5) + p] = o;
  }
}

extern "C" void kernel_launch(void* const* d_in, const int* in_sizes, int n_in,
                              void* d_out, int out_size, void* d_ws, size_t ws_size,
                              hipStream_t stream){
  const float* x   = (const float*)d_in[0];
  const int*   ei  = (const int*)d_in[1];
  const float* W0  = (const float*)d_in[2];
  const float* as0 = (const float*)d_in[3];
  const float* ad0 = (const float*)d_in[4];
  const float* b0  = (const float*)d_in[5];
  const float* W1  = (const float*)d_in[6];
  const float* as1 = (const float*)d_in[7];
  const float* ad1 = (const float*)d_in[8];
  const float* b1  = (const float*)d_in[9];
  const float* W2  = (const float*)d_in[10];
  const float* as2 = (const float*)d_in[11];
  const float* ad2 = (const float*)d_in[12];
  const float* b2  = (const float*)d_in[13];
  int N = in_sizes[0] / 256;
  int E = in_sizes[1] / 2;
  int Etot = E + N;

  size_t off = 0;
  auto alc = [&](size_t bytes) -> char* {
    char* p = (char*)d_ws + off;
    off += (bytes + 255) & ~(size_t)255;
    return p;
  };
  ushort_t* xb    = (ushort_t*)alc((size_t)N * 256 * 2); // x bf16; g1b aliases
  ushort_t* h0b   = (ushort_t*)alc((size_t)N * 256 * 2); // h0 bf16; g2b aliases
  float*    als   = (float*)alc((size_t)N * 4 * 4);      // layer0, 4 heads
  float*    ald   = (float*)alc((size_t)N * 4 * 4);
  float*    als1  = (float*)alc((size_t)N * 4);
  float*    ald1  = (float*)alc((size_t)N * 4);
  float*    als2  = (float*)alc((size_t)N * 4);
  float*    ald2  = (float*)alc((size_t)N * 4);
  int*      esrc  = (int*)alc((size_t)Etot * 4);
  int*      rowptr= (int*)alc((size_t)(N + 1) * 4);
  int*      cnt   = (int*)alc((size_t)N * 4);
  int*      cursor= (int*)alc((size_t)N * 4);
  int*      bsum  = (int*)alc(256 * 4);
  ushort_t* W0p   = (ushort_t*)alc(256 * 256 * 2);
  ushort_t* W1p   = (ushort_t*)alc(256 * 64 * 2);
  ushort_t* W2p   = (ushort_t*)alc(64 * 64 * 2);

  ushort_t* g1b = xb;                      // xb dead after gemm0
  ushort_t* g2b = h0b;                     // h0b dead after agg0g1

  int nb = (N + 255) / 256;
  int eb = (Etot + 255) / 256;
  int fb = (N * 64 + 255) / 256;
  int g0b = (N + 31) / 32;                 // gemm0: 32 rows/block
  int tb = (N + 15) / 16;                  // fused agg blocks: 16 nodes each
  int ab = (N + 3) / 4;                    // final agg: 4 nodes/block

  // ---- prep: hist + x->bf16 + weight transposes ----
  hipMemsetAsync(cnt, 0, (size_t)N * 4, stream);
  prep_kernel<<<eb + fb + 336, 256, 0, stream>>>(ei, cnt, (const float4*)x,
                                                 (ushort4*)xb, N * 64,
                                                 W0, W0p, W1, W1p, W2, W2p,
                                                 E, Etot, eb, fb);
  blocksum_kernel<<<nb, 256, 0, stream>>>(cnt, bsum, N);
  scanb_kernel<<<1, 256, 0, stream>>>(bsum, nb);
  scan2_kernel<<<nb, 256, 0, stream>>>(cnt, bsum, rowptr, cursor, N, Etot);
  scatter_kernel<<<eb, 256, 0, stream>>>(ei, cursor, esrc, E, Etot);

  // ---- Layer 0 GEMM ----
  gemm0_kernel<<<g0b, 256, 0, stream>>>(xb, W0p, h0b, as0, ad0, als, ald, N);

  // ---- Layer 0 agg + Layer 1 GEMM (fused) ----
  agg0g1_kernel<<<tb, 256, 0, stream>>>(rowptr, esrc, (const uint2*)h0b,
                                        als, ald, b0, W1p, as1, ad1,
                                        g1b, als1, ald1, N);

  // ---- Layer 1 agg + Layer 2 GEMM (fused) ----
  agg1g2_kernel<<<tb, 256, 0, stream>>>(rowptr, esrc, (const unsigned*)g1b,
                                        als1, ald1, b1, W2p, as2, ad2,
                                        g2b, als2, ald2, N);

  // ---- Layer 2 agg -> output ----
  aggF_kernel<<<ab, 256, 0, stream>>>(rowptr, esrc, (const unsigned*)g2b,
                                      als2, ald2, b2, (float2*)d_out, N);
}